// Round 20
// baseline (1370.992 us; speedup 1.0000x reference)
//
#include <hip/hip_runtime.h>
#include <math.h>

#define S_LEN 1024
#define D_MODEL 768
#define NHEAD 12
#define NEG_INF -3.4028234663852886e38f

#define QT 32           // queries per attention block
#define KB 288          // key band per block = QT + 2*128

typedef _Float16 f16x8 __attribute__((ext_vector_type(8)));
typedef __attribute__((ext_vector_type(4))) float f32x4;

typedef const __attribute__((address_space(1))) unsigned int ga_u32;
typedef __attribute__((address_space(3))) unsigned int ls_u32;
__device__ __forceinline__ void gload16(const void* g, void* l) {
  __builtin_amdgcn_global_load_lds((ga_u32*)g, (ls_u32*)l, 16, 0, 0);
}

__device__ __forceinline__ float gelu_exact(float v) {
  return 0.5f * v * (1.0f + erff(v * 0.7071067811865475f));
}
__device__ __forceinline__ unsigned short f2h(float f) {
  union { _Float16 h; unsigned short u; } x; x.h = (_Float16)f; return x.u;
}

// ---------------- PE table init: pe[s][d], 1024x768 ----------------
__global__ __launch_bounds__(256) void pe_init(float* __restrict__ pe) {
  int i = blockIdx.x * 256 + threadIdx.x;
  if (i >= S_LEN * D_MODEL) return;
  int d = i % D_MODEL;
  int s = i / D_MODEL;
  float div = expf((float)(d & ~1) * (-9.210340371976184f / 768.0f));
  float ang = (float)s * div;
  pe[i] = (d & 1) ? cosf(ang) : sinf(ang);
}

// ---------------- embedding + PE table add (float4) ----------------
__global__ __launch_bounds__(256) void embed_kernel(
    const int* __restrict__ tok, const float* __restrict__ emb,
    const float* __restrict__ pe, float* __restrict__ X, int total4) {
  int i = blockIdx.x * 256 + threadIdx.x;
  if (i >= total4) return;
  int d4 = i % 192;
  int bs = i / 192;
  int s = bs & (S_LEN - 1);
  int t = tok[bs];
  float4 e = ((const float4*)emb)[(size_t)t * 192 + d4];
  float4 p = ((const float4*)pe)[(size_t)s * 192 + d4];
  float4 o; o.x = e.x + p.x; o.y = e.y + p.y; o.z = e.z + p.z; o.w = e.w + p.w;
  ((float4*)X)[i] = o;
}

// ---------------- weight convert: fp32 -> fp16 ----------------
__global__ __launch_bounds__(256) void cvt_w_h(
    const float* __restrict__ W, unsigned short* __restrict__ H, int n4) {
  int i = blockIdx.x * 256 + threadIdx.x;
  if (i >= n4) return;
  float4 w = ((const float4*)W)[i];
  ushort4 h;
  h.x = f2h(w.x); h.y = f2h(w.y); h.z = f2h(w.z); h.w = f2h(w.w);
  ((ushort4*)H)[i] = h;
}

// ---------------- LayerNorm over D=768 -> fp16 (192 thr, float4/lane) ----------
__global__ __launch_bounds__(192) void ln_kernel(
    const float* __restrict__ X, const float* __restrict__ gam,
    const float* __restrict__ bet, unsigned short* __restrict__ Y) {
  __shared__ float scratch[3];
  const int row = blockIdx.x;
  const int tid = threadIdx.x;
  const int d = tid << 2;
  float4 v = *(const float4*)(X + (size_t)row * D_MODEL + d);
  float s = v.x + v.y + v.z + v.w;
#pragma unroll
  for (int o = 32; o; o >>= 1) s += __shfl_xor(s, o, 64);
  if ((tid & 63) == 0) scratch[tid >> 6] = s;
  __syncthreads();
  float mean = (scratch[0] + scratch[1] + scratch[2]) * (1.0f / 768.0f);
  __syncthreads();
  float d0 = v.x - mean, d1 = v.y - mean, d2 = v.z - mean, d3 = v.w - mean;
  float ss = d0 * d0 + d1 * d1 + d2 * d2 + d3 * d3;
#pragma unroll
  for (int o = 32; o; o >>= 1) ss += __shfl_xor(ss, o, 64);
  if ((tid & 63) == 0) scratch[tid >> 6] = ss;
  __syncthreads();
  float var = (scratch[0] + scratch[1] + scratch[2]) * (1.0f / 768.0f);
  float rstd = rsqrtf(var + 1e-5f);
  float4 g = *(const float4*)(gam + d);
  float4 bb = *(const float4*)(bet + d);
  ushort4 o4;
  o4.x = f2h(d0 * rstd * g.x + bb.x);
  o4.y = f2h(d1 * rstd * g.y + bb.y);
  o4.z = f2h(d2 * rstd * g.z + bb.z);
  o4.w = f2h(d3 * rstd * g.w + bb.w);
  *(ushort4*)(Y + (size_t)row * D_MODEL + d) = o4;
}

// ---------------- gemm128: 128x128 tile, BK=32, 4 waves, single-barrier 3-buffer --
// XCD chunk + 8x2 super-tile remap keeps per-XCD L2 working set ~2 MB.
// EPI 0: C_f16 = acc+bias   1: gelu   2: C_f32 += acc+bias (residual RMW)
template <int EPI>
__global__ __launch_bounds__(256) void gemm128(
    const unsigned short* __restrict__ A, const unsigned short* __restrict__ W,
    const float* __restrict__ bias, void* __restrict__ Cv,
    int N, int K, int NX) {
  __shared__ __align__(16) unsigned short SH[24576];  // 3 buffers x (A 8KB + B 8KB)
  const int tid = threadIdx.x;
  const int nwg = gridDim.x;
  const int wg = ((blockIdx.x & 7) * (nwg >> 3)) + (blockIdx.x >> 3);
  const int SX = NX >> 1;
  const int st = wg >> 4, w16 = wg & 15;
  const int ty = (st / SX) * 8 + (w16 >> 1);
  const int tx = (st % SX) * 2 + (w16 & 1);
  const int m0 = ty << 7, n0 = tx << 7;
  const int wave = tid >> 6, lane = tid & 63;
  const int wr = (wave >> 1) << 6, wc = (wave & 1) << 6;
  const int lq = lane >> 4, lr = lane & 15;
  const int rA0 = (wave << 5) + (lane >> 2);
  const int rA1 = rA0 + 16;
  const int sl = lane & 3;
  const size_t gA0 = (size_t)(m0 + rA0) * K + ((sl ^ ((rA0 >> 1) & 3)) << 3);
  const size_t gA1 = (size_t)(m0 + rA1) * K + ((sl ^ ((rA1 >> 1) & 3)) << 3);
  const size_t gB0 = (size_t)(n0 + rA0) * K + ((sl ^ ((rA0 >> 1) & 3)) << 3);
  const size_t gB1 = (size_t)(n0 + rA1) * K + ((sl ^ ((rA1 >> 1) & 3)) << 3);
  const int lws = wave << 10;

  const int nt = K >> 5;
  auto stage = [&](int buf, int t) {
    unsigned short* base = SH + (buf << 13);
    const int kk = t << 5;
    gload16(A + gA0 + kk, base + lws);
    gload16(A + gA1 + kk, base + lws + 512);
    gload16(W + gB0 + kk, base + 4096 + lws);
    gload16(W + gB1 + kk, base + 4096 + lws + 512);
  };
  stage(0, 0);
  stage(1, 1);

  f32x4 acc[4][4] = {};
  int cb = 0;                         // compute-buffer index (cycles 0,1,2)
  for (int t = 0; t < nt; ++t) {
    if (t + 1 < nt) {
      asm volatile("s_waitcnt vmcnt(4)" ::: "memory");   // tile t's 4 loads done
    } else {
      asm volatile("s_waitcnt vmcnt(0)" ::: "memory");
    }
    __builtin_amdgcn_s_barrier();                         // everyone's tile t ready
    __builtin_amdgcn_sched_barrier(0);
    const unsigned short* As = SH + (cb << 13);
    const unsigned short* Bs = As + 4096;
    f16x8 af[4], bq[4];
#pragma unroll
    for (int i = 0; i < 4; ++i) {
      int r = wr + (i << 4) + lr;
      af[i] = *(const f16x8*)&As[r * 32 + ((lq ^ ((r >> 1) & 3)) << 3)];
    }
#pragma unroll
    for (int j = 0; j < 4; ++j) {
      int r = wc + (j << 4) + lr;
      bq[j] = *(const f16x8*)&Bs[r * 32 + ((lq ^ ((r >> 1) & 3)) << 3)];
    }
    if (t + 2 < nt) {                 // stage overlaps the MFMA cluster
      int sb = cb + 2; if (sb >= 3) sb -= 3;
      stage(sb, t + 2);
    }
    __builtin_amdgcn_sched_barrier(0);                    // pin stage before MFMAs
    __builtin_amdgcn_s_setprio(1);
#pragma unroll
    for (int i = 0; i < 4; ++i)
#pragma unroll
      for (int j = 0; j < 4; ++j)
        acc[i][j] = __builtin_amdgcn_mfma_f32_16x16x32_f16(af[i], bq[j], acc[i][j], 0, 0, 0);
    __builtin_amdgcn_s_setprio(0);
    cb = (cb == 2) ? 0 : cb + 1;
  }
  // bias per j-fragment column
  float bval[4];
#pragma unroll
  for (int j = 0; j < 4; ++j) bval[j] = bias[n0 + wc + (j << 4) + lr];

  if (EPI == 2) {
    // residual RMW epilogue (fp32 C)
    float* C = (float*)Cv;
#pragma unroll
    for (int j = 0; j < 4; ++j) {
      const int gcol = n0 + wc + (j << 4) + lr;
#pragma unroll
      for (int i = 0; i < 4; ++i) {
        const int grow0 = m0 + wr + (i << 4) + (lq << 2);
#pragma unroll
        for (int r = 0; r < 4; ++r) {
          size_t off = (size_t)(grow0 + r) * N + gcol;
          C[off] += acc[i][j][r] + bval[j];
        }
      }
    }
    return;
  }

  unsigned short* C = (unsigned short*)Cv;
  __syncthreads();
  // repacked epilogue: two 64-row halves through LDS buffer 0, 16B/lane stores
#pragma unroll
  for (int hh = 0; hh < 2; ++hh) {
    if ((wave >> 1) == hh) {
#pragma unroll
      for (int i = 0; i < 4; ++i)
#pragma unroll
        for (int j = 0; j < 4; ++j) {
          const int colb = wc + (j << 4) + lr;
#pragma unroll
          for (int r = 0; r < 4; ++r) {
            const int rowl = (i << 4) + (lq << 2) + r;
            float v = acc[i][j][r] + bval[j];
            if (EPI == 1) v = gelu_exact(v);
            const int ch = (colb >> 3) ^ (rowl & 7);
            SH[rowl * 128 + (ch << 3) + (colb & 7)] = f2h(v);
          }
        }
    }
    __syncthreads();
#pragma unroll
    for (int it = 0; it < 4; ++it) {
      const int cid = tid + (it << 8);
      const int row = cid >> 4, ch = cid & 15;
      uint4 v8 = *(uint4*)&SH[row * 128 + ((ch ^ (row & 7)) << 3)];
      *(uint4*)&C[(size_t)(m0 + (hh << 6) + row) * N + n0 + (ch << 3)] = v8;
    }
    __syncthreads();
  }
}

// ---------------- banded attention: MFMA QK^T + softmax + MFMA PV (fp16) ---------
// grid (b, qtile): XCD = b. Single-barrier softmax combine (local-max exp).
__global__ __launch_bounds__(512) void attn_kernel(
    const unsigned short* __restrict__ qkv, const int* __restrict__ mask,
    unsigned short* __restrict__ attn_out, float* __restrict__ allw) {
  __shared__ __align__(16) unsigned short Ks[KB * 72];
  __shared__ __align__(16) unsigned short Vt[64 * 328];
  __shared__ __align__(16) unsigned short Qs[32 * 72];
  __shared__ __align__(16) unsigned short Ps[32 * 328];
  __shared__ __align__(16) float redmax[2][16][4];
  __shared__ __align__(16) float redsum[2][16][4];
  __shared__ int kvalid[KB];

  const int qt0 = blockIdx.y * QT;
  const int b = blockIdx.x;
  const int tid = threadIdx.x;
  const int w = tid >> 6, lane = tid & 63;
  const int lr = lane & 15, lg = lane >> 4;
  const int k0 = qt0 - 128;
  const int qh = w & 1, wq = w >> 1;
  const int nkt = (wq < 2) ? 5 : 4;

  for (int j = tid; j < KB; j += 512) {
    int key = k0 + j;
    kvalid[j] = (key >= 0 && key < S_LEN && mask[b * S_LEN + key] != 0) ? 1 : 0;
  }

  f32x4 pm[5] = {};
  const size_t rowbase = (size_t)(b * S_LEN) * 2304;
  const int qloc = lg << 2;
  const int qbase = (qh << 4) + qloc;

  for (int h = 0; h < NHEAD; ++h) {
    const int hoff = h << 6;
    if (tid < 256) {
      int r = tid >> 3, c = tid & 7;
      uint4 v = *(const uint4*)(qkv + rowbase + (size_t)(qt0 + r) * 2304 + hoff + (c << 3));
      *(uint4*)&Qs[r * 72 + ((c ^ (r & 7)) << 3)] = v;
    }
    for (int idx = tid; idx < 2304; idx += 512) {
      int r = idx >> 3, c = idx & 7;
      int key = k0 + r;
      uint4 kv = {0, 0, 0, 0}, vv = {0, 0, 0, 0};
      if ((unsigned)key < (unsigned)S_LEN) {
        const unsigned short* base = qkv + rowbase + (size_t)key * 2304 + hoff + (c << 3);
        kv = *(const uint4*)(base + 768);
        vv = *(const uint4*)(base + 1536);
      }
      *(uint4*)&Ks[r * 72 + ((c ^ (r & 7)) << 3)] = kv;
      const unsigned short* ve = (const unsigned short*)&vv;
      int jc = r >> 3, jw = r & 7;
#pragma unroll
      for (int e = 0; e < 8; ++e) {
        int d = (c << 3) + e;
        Vt[d * 328 + ((jc ^ ((d >> 2) & 7)) << 3) + jw] = ve[e];
      }
    }
    __syncthreads();

    f16x8 aq[2];
#pragma unroll
    for (int kc = 0; kc < 2; ++kc) {
      int r = (qh << 4) + lr;
      aq[kc] = *(f16x8*)&Qs[r * 72 + ((((kc << 2) + lg) ^ (r & 7)) << 3)];
    }
    f32x4 sc[5];
    __builtin_amdgcn_s_setprio(1);
#pragma unroll
    for (int t = 0; t < 5; ++t) {
      sc[t] = (f32x4){0.0f, 0.0f, 0.0f, 0.0f};
      if (t < nkt) {
        int r = ((wq + (t << 2)) << 4) + lr;
#pragma unroll
        for (int kc = 0; kc < 2; ++kc) {
          f16x8 bk = *(f16x8*)&Ks[r * 72 + ((((kc << 2) + lg) ^ (r & 7)) << 3)];
          sc[t] = __builtin_amdgcn_mfma_f32_16x16x32_f16(aq[kc], bk, sc[t], 0, 0, 0);
        }
      }
    }
    __builtin_amdgcn_s_setprio(0);
#pragma unroll
    for (int t = 0; t < 5; ++t) if (t < nkt) {
      int j = ((wq + (t << 2)) << 4) + lr;
      int okk = kvalid[j];
#pragma unroll
      for (int rg = 0; rg < 4; ++rg) {
        int q = qbase + rg;
        float s = sc[t][rg] * 0.125f;
        sc[t][rg] = (okk && j >= q && j <= q + 256) ? s : NEG_INF;
      }
    }
    // ---- single-barrier softmax: local-max exp, combine (m_w, z_w) pairs ----
    float mx[4], zs[4];
#pragma unroll
    for (int rg = 0; rg < 4; ++rg) {
      float m = NEG_INF;
#pragma unroll
      for (int t = 0; t < 5; ++t) if (t < nkt) m = fmaxf(m, sc[t][rg]);
      mx[rg] = m;
    }
#pragma unroll
    for (int o = 1; o < 16; o <<= 1)
#pragma unroll
      for (int rg = 0; rg < 4; ++rg) mx[rg] = fmaxf(mx[rg], __shfl_xor(mx[rg], o, 64));
#pragma unroll
    for (int rg = 0; rg < 4; ++rg) { mx[rg] = fmaxf(mx[rg], -1e30f); zs[rg] = 0.0f; }
#pragma unroll
    for (int t = 0; t < 5; ++t) if (t < nkt)
#pragma unroll
      for (int rg = 0; rg < 4; ++rg) {
        float e = expf(sc[t][rg] - mx[rg]);
        sc[t][rg] = e;
        zs[rg] += e;
      }
#pragma unroll
    for (int o = 1; o < 16; o <<= 1)
#pragma unroll
      for (int rg = 0; rg < 4; ++rg) zs[rg] += __shfl_xor(zs[rg], o, 64);
    if (lr == 0)
#pragma unroll
      for (int rg = 0; rg < 4; ++rg) {
        redmax[qh][qloc + rg][wq] = mx[rg];
        redsum[qh][qloc + rg][wq] = zs[rg];
      }
    __syncthreads();
#pragma unroll
    for (int rg = 0; rg < 4; ++rg) {
      f32x4 vm = *(f32x4*)&redmax[qh][qloc + rg][0];
      f32x4 vz = *(f32x4*)&redsum[qh][qloc + rg][0];
      float M = fmaxf(fmaxf(vm[0], vm[1]), fmaxf(vm[2], vm[3]));
      float Z = vz[0] * expf(vm[0] - M) + vz[1] * expf(vm[1] - M)
              + vz[2] * expf(vm[2] - M) + vz[3] * expf(vm[3] - M);
      zs[rg] = expf(mx[rg] - M) / Z;        // per-wave normalize factor
    }
#pragma unroll
    for (int t = 0; t < 5; ++t) if (t < nkt) {
      int j = ((wq + (t << 2)) << 4) + lr;
      int pc = j >> 3, pw = j & 7;
#pragma unroll
      for (int rg = 0; rg < 4; ++rg) {
        float p = sc[t][rg] * zs[rg];
        pm[t][rg] += p;
        int row = qbase + rg;
        Ps[row * 328 + ((pc ^ (row & 7)) << 3) + pw] = f2h(p);
      }
    }
    __syncthreads();
    {
      const int qt = w >> 2, dt = w & 3;
      const int ra = (qt << 4) + lr;
      const int rd = (dt << 4) + lr;
      f32x4 o4 = {0.0f, 0.0f, 0.0f, 0.0f};
      __builtin_amdgcn_s_setprio(1);
#pragma unroll
      for (int ks = 0; ks < 9; ++ks) {
        f16x8 pa = *(f16x8*)&Ps[ra * 328 + ((((ks << 2) + lg) ^ (ra & 7)) << 3)];
        f16x8 vb = *(f16x8*)&Vt[rd * 328 + ((((ks << 2) + lg) ^ ((rd >> 2) & 7)) << 3)];
        o4 = __builtin_amdgcn_mfma_f32_16x16x32_f16(pa, vb, o4, 0, 0, 0);
      }
      __builtin_amdgcn_s_setprio(0);
      unsigned short* op = attn_out +
          ((size_t)(b * S_LEN + qt0 + (qt << 4) + (lg << 2))) * D_MODEL + hoff + (dt << 4) + lr;
#pragma unroll
      for (int rg = 0; rg < 4; ++rg) op[(size_t)rg * D_MODEL] = f2h(o4[rg]);
    }
    __syncthreads();
  }

#pragma unroll
  for (int t = 0; t < 5; ++t) if (t < nkt) {
    int j = ((wq + (t << 2)) << 4) + lr;
    int key = k0 + j;
    if ((unsigned)key < (unsigned)S_LEN) {
      float* ap = allw + ((size_t)(b * S_LEN) + qt0 + qbase) * S_LEN + key;
#pragma unroll
      for (int rg = 0; rg < 4; ++rg) ap[(size_t)rg * S_LEN] = pm[t][rg] * (1.0f / 12.0f);
    }
  }
}

// ---------------- pooling stage 1: scores sc[b,s] = x·pool_w + pool_b ----------
__global__ __launch_bounds__(256) void pool_score(
    const float* __restrict__ X, const int* __restrict__ mask,
    const float* __restrict__ pool_w, const float* __restrict__ pool_b,
    float* __restrict__ sc) {
  const int tid = threadIdx.x;
  const int wave = tid >> 6, lane = tid & 63;
  const int row = blockIdx.x * 4 + wave;
  const float* xr = X + (size_t)row * D_MODEL;
  float acc = 0.0f;
#pragma unroll
  for (int c = 0; c < 3; ++c) {
    int d = (lane << 2) + (c << 8);
    float4 xv = *(const float4*)(xr + d);
    float4 wv = *(const float4*)(pool_w + d);
    acc += xv.x * wv.x + xv.y * wv.y + xv.z * wv.z + xv.w * wv.w;
  }
#pragma unroll
  for (int o = 32; o; o >>= 1) acc += __shfl_xor(acc, o, 64);
  if (lane == 0)
    sc[row] = (mask[row] == 0) ? NEG_INF : (acc + pool_b[0]);
}

// ---------------- pooling stage 2: softmax over S per batch (in-place) ---------
__global__ __launch_bounds__(256) void pool_softmax(float* __restrict__ sc) {
  __shared__ float scratch[4];
  __shared__ float buf[S_LEN];
  const int b = blockIdx.x;
  const int tid = threadIdx.x;
  float* sb = sc + b * S_LEN;
  float m = NEG_INF;
  for (int s = tid; s < S_LEN; s += 256) { buf[s] = sb[s]; m = fmaxf(m, buf[s]); }
#pragma unroll
  for (int o = 32; o; o >>= 1) m = fmaxf(m, __shfl_xor(m, o, 64));
  if ((tid & 63) == 0) scratch[tid >> 6] = m;
  __syncthreads();
  m = fmaxf(fmaxf(scratch[0], scratch[1]), fmaxf(scratch[2], scratch[3]));
  __syncthreads();
  float z = 0.0f;
  for (int s = tid; s < S_LEN; s += 256) { float e = expf(buf[s] - m); buf[s] = e; z += e; }
#pragma unroll
  for (int o = 32; o; o >>= 1) z += __shfl_xor(z, o, 64);
  if ((tid & 63) == 0) scratch[tid >> 6] = z;
  __syncthreads();
  float Z = scratch[0] + scratch[1] + scratch[2] + scratch[3];
  const float inv = 1.0f / Z;
  for (int s = tid; s < S_LEN; s += 256) sb[s] = buf[s] * inv;
}

// ---------------- pooling stage 3: partial weighted sums over s-chunks ---------
__global__ __launch_bounds__(256) void pool_sum(
    const float* __restrict__ X, const float* __restrict__ wgt,
    float* __restrict__ partial) {
  const int bx = blockIdx.x;            // dchunk*8 + schunk
  const int b = blockIdx.y;
  const int dchunk = bx >> 3, schunk = bx & 7;
  const int d = (dchunk << 8) + threadIdx.x;
  const int s0 = schunk << 7;
  const float* xb = X + ((size_t)(b << 10) + s0) * D_MODEL + d;
  const float* wb = wgt + (b << 10) + s0;
  float acc = 0.0f;
  for (int s = 0; s < 128; ++s) acc += wb[s] * xb[(size_t)s * D_MODEL];
  partial[((size_t)((b << 3) + schunk)) * D_MODEL + d] = acc;
}

// ---------------- classifier stage A: reduce partials, tanh, LN -> cbuf --------
__global__ __launch_bounds__(256) void cls_ln(
    const float* __restrict__ partial,
    const float* __restrict__ ln_s, const float* __restrict__ ln_b,
    float* __restrict__ cbuf_g) {
  const int b = blockIdx.x;
  const int tid = threadIdx.x;
  __shared__ float scratch[4];
  __shared__ __align__(16) float pbuf[D_MODEL];
  for (int d = tid; d < D_MODEL; d += 256) {
    float acc = 0.0f;
#pragma unroll
    for (int p = 0; p < 8; ++p) acc += partial[((size_t)((b << 3) + p)) * D_MODEL + d];
    pbuf[d] = tanhf(acc);
  }
  __syncthreads();
  float ls = 0.0f;
  for (int d = tid; d < D_MODEL; d += 256) ls += pbuf[d];
#pragma unroll
  for (int o = 32; o; o >>= 1) ls += __shfl_xor(ls, o, 64);
  if ((tid & 63) == 0) scratch[tid >> 6] = ls;
  __syncthreads();
  float mean = (scratch[0] + scratch[1] + scratch[2] + scratch[3]) * (1.0f / 768.0f);
  __syncthreads();
  float vs = 0.0f;
  for (int d = tid; d < D_MODEL; d += 256) { float dd = pbuf[d] - mean; vs += dd * dd; }
#pragma unroll
  for (int o = 32; o; o >>= 1) vs += __shfl_xor(vs, o, 64);
  if ((tid & 63) == 0) scratch[tid >> 6] = vs;
  __syncthreads();
  float var = (scratch[0] + scratch[1] + scratch[2] + scratch[3]) * (1.0f / 768.0f);
  float rstd = rsqrtf(var + 1e-5f);
  for (int d = tid; d < D_MODEL; d += 256)
    cbuf_g[b * D_MODEL + d] = (pbuf[d] - mean) * rstd * ln_s[d] + ln_b[d];
}

// ---------------- classifier stage B: c1[b,i] = tanh(cbuf·w1[i] + b1[i]) --------
__global__ __launch_bounds__(256) void cls_mlp1(
    const float* __restrict__ cbuf_g, const float* __restrict__ w1,
    const float* __restrict__ b1, float* __restrict__ c1_g) {
  const int tid = threadIdx.x;
  const int wave = tid >> 6, lane = tid & 63;
  const int i = blockIdx.x * 4 + wave;
  const int b = blockIdx.y;
  __shared__ __align__(16) float cb[D_MODEL];
  for (int d = tid; d < D_MODEL; d += 256) cb[d] = cbuf_g[b * D_MODEL + d];
  __syncthreads();
  const float* wr = w1 + (size_t)i * D_MODEL;
  float acc = 0.0f;
#pragma unroll
  for (int c = 0; c < 3; ++c) {
    int d = (lane << 2) + (c << 8);
    float4 wv = *(const float4*)(wr + d);
    float4 cv = *(const float4*)(&cb[d]);
    acc += wv.x * cv.x + wv.y * cv.y + wv.z * cv.z + wv.w * cv.w;
  }
#pragma unroll
  for (int o = 32; o; o >>= 1) acc += __shfl_xor(acc, o, 64);
  if (lane == 0) c1_g[b * D_MODEL + i] = tanhf(acc + b1[i]);
}

// ---------------- classifier stage C: logits ----------------
__global__ __launch_bounds__(256) void cls_logits(
    const float* __restrict__ c1_g, const float* __restrict__ w2,
    const float* __restrict__ b2, float* __restrict__ out) {
  const int b = blockIdx.x;
  const int tid = threadIdx.x;
  __shared__ float scratch[4];
#pragma unroll
  for (int jc = 0; jc < 2; ++jc) {
    float acc = 0.0f;
    for (int i = tid; i < D_MODEL; i += 256) acc += c1_g[b * D_MODEL + i] * w2[jc * D_MODEL + i];
#pragma unroll
    for (int o = 32; o; o >>= 1) acc += __shfl_xor(acc, o, 64);
    if ((tid & 63) == 0) scratch[tid >> 6] = acc;
    __syncthreads();
    if (tid == 0) out[b * 2 + jc] = scratch[0] + scratch[1] + scratch[2] + scratch[3] + b2[jc];
    __syncthreads();
  }
}

extern "C" void kernel_launch(void* const* d_in, const int* in_sizes, int n_in,
                              void* d_out, int out_size, void* d_ws, size_t ws_size,
                              hipStream_t stream) {
  const int*   tokens  = (const int*)d_in[0];
  const int*   mask    = (const int*)d_in[1];
  const float* emb     = (const float*)d_in[2];
  const float* in_w    = (const float*)d_in[3];
  const float* in_b    = (const float*)d_in[4];
  const float* out_w   = (const float*)d_in[5];
  const float* out_b   = (const float*)d_in[6];
  const float* ln1_s   = (const float*)d_in[7];
  const float* ln1_b   = (const float*)d_in[8];
  const float* ln2_s   = (const float*)d_in[9];
  const float* ln2_b   = (const float*)d_in[10];
  const float* ff_w1   = (const float*)d_in[11];
  const float* ff_b1   = (const float*)d_in[12];
  const float* ff_w2   = (const float*)d_in[13];
  const float* ff_b2   = (const float*)d_in[14];
  const float* pool_w  = (const float*)d_in[15];
  const float* pool_b  = (const float*)d_in[16];
  const float* cls_ln_s = (const float*)d_in[17];
  const float* cls_ln_b = (const float*)d_in[18];
  const float* cls_w1  = (const float*)d_in[19];
  const float* cls_b1  = (const float*)d_in[20];
  const float* cls_w2  = (const float*)d_in[21];
  const float* cls_b2  = (const float*)d_in[22];

  float* outp = (float*)d_out;
  float* ws = (float*)d_ws;
  const size_t XN = (size_t)8 * 1024 * 768;          // 6,291,456
  const size_t BIGU = (size_t)8192 * 3072;           // 25,165,824 ushorts
  float* x = ws;
  unsigned short* bigu = (unsigned short*)(ws + XN);             // fp16 qkv / gelu
  unsigned short* h_f16 = (unsigned short*)(ws + XN + BIGU / 2); // fp16 activations
  unsigned short* wall = h_f16 + XN;                             // fp16 weight arena
  unsigned short* wall_in  = wall;                               // 4*2304*768
  unsigned short* wall_out = wall + (size_t)7077888;             // 4*768*768
  unsigned short* wall_ff1 = wall + (size_t)9437184;             // 4*3072*768
  unsigned short* wall_ff2 = wall + (size_t)18874368;            // 4*768*3072
  float* clsbuf = (float*)(wall + (size_t)28311552);
  float* sc_ws = clsbuf;                                         // 8192 floats
  float* partial = clsbuf + 8192;                                // 49152 floats
  float* cbuf_ws = partial + 49152;                              // 6144 floats
  float* c1_ws = cbuf_ws + 6144;                                 // 6144 floats
  float* pe_ws = c1_ws + 6144;                                   // 786432 floats
  float* allw = outp + 16;

  hipMemsetAsync(d_out, 0, (size_t)out_size * sizeof(float), stream);

  // PE table + upfront weight conversion (all layers)
  pe_init<<<3072, 256, 0, stream>>>(pe_ws);
  cvt_w_h<<<6912, 256, 0, stream>>>(in_w,  wall_in,  1769472);
  cvt_w_h<<<2304, 256, 0, stream>>>(out_w, wall_out,  589824);
  cvt_w_h<<<9216, 256, 0, stream>>>(ff_w1, wall_ff1, 2359296);
  cvt_w_h<<<9216, 256, 0, stream>>>(ff_w2, wall_ff2, 2359296);

  const int total4 = (int)(XN >> 2);
  embed_kernel<<<(total4 + 255) / 256, 256, 0, stream>>>(tokens, emb, pe_ws, x, total4);

  for (int l = 0; l < 4; ++l) {
    ln_kernel<<<8192, 192, 0, stream>>>(x, ln1_s + l * 768, ln1_b + l * 768, h_f16);
    gemm128<0><<<1152, 256, 0, stream>>>(h_f16, wall_in + (size_t)l * 1769472,
                                         in_b + l * 2304, bigu, 2304, 768, 18);
    attn_kernel<<<dim3(8, S_LEN / QT), 512, 0, stream>>>(bigu, mask, h_f16,
                                                         allw + (size_t)l * 8 * 1024 * 1024);
    gemm128<2><<<384, 256, 0, stream>>>(h_f16, wall_out + (size_t)l * 589824,
                                        out_b + l * 768, x, 768, 768, 6);
    ln_kernel<<<8192, 192, 0, stream>>>(x, ln2_s + l * 768, ln2_b + l * 768, h_f16);
    gemm128<1><<<1536, 256, 0, stream>>>(h_f16, wall_ff1 + (size_t)l * 2359296,
                                         ff_b1 + l * 3072, bigu, 3072, 768, 24);
    gemm128<2><<<384, 256, 0, stream>>>(bigu, wall_ff2 + (size_t)l * 2359296,
                                        ff_b2 + l * 768, x, 768, 3072, 6);
  }

  pool_score<<<2048, 256, 0, stream>>>(x, mask, pool_w, pool_b, sc_ws);
  pool_softmax<<<8, 256, 0, stream>>>(sc_ws);
  pool_sum<<<dim3(24, 8), 256, 0, stream>>>(x, sc_ws, partial);
  cls_ln<<<8, 256, 0, stream>>>(partial, cls_ln_s, cls_ln_b, cbuf_ws);
  cls_mlp1<<<dim3(192, 8), 256, 0, stream>>>(cbuf_ws, cls_w1, cls_b1, c1_ws);
  cls_logits<<<8, 256, 0, stream>>>(c1_ws, cls_w2, cls_b2, outp);
}

// Round 21
// 1346.884 us; speedup vs baseline: 1.0179x; 1.0179x over previous
//
#include <hip/hip_runtime.h>
#include <math.h>

#define S_LEN 1024
#define D_MODEL 768
#define NHEAD 12
#define NEG_INF -3.4028234663852886e38f

#define QT 32           // queries per attention block
#define KB 288          // key band per block = QT + 2*128

typedef _Float16 f16x8 __attribute__((ext_vector_type(8)));
typedef __attribute__((ext_vector_type(4))) float f32x4;

typedef const __attribute__((address_space(1))) unsigned int ga_u32;
typedef __attribute__((address_space(3))) unsigned int ls_u32;
__device__ __forceinline__ void gload16(const void* g, void* l) {
  __builtin_amdgcn_global_load_lds((ga_u32*)g, (ls_u32*)l, 16, 0, 0);
}

__device__ __forceinline__ float gelu_exact(float v) {
  return 0.5f * v * (1.0f + erff(v * 0.7071067811865475f));
}
__device__ __forceinline__ unsigned short f2h(float f) {
  union { _Float16 h; unsigned short u; } x; x.h = (_Float16)f; return x.u;
}

// ---------------- PE table init: pe[s][d], 1024x768 ----------------
__global__ __launch_bounds__(256) void pe_init(float* __restrict__ pe) {
  int i = blockIdx.x * 256 + threadIdx.x;
  if (i >= S_LEN * D_MODEL) return;
  int d = i % D_MODEL;
  int s = i / D_MODEL;
  float div = expf((float)(d & ~1) * (-9.210340371976184f / 768.0f));
  float ang = (float)s * div;
  pe[i] = (d & 1) ? cosf(ang) : sinf(ang);
}

// ---------------- embedding + PE table add ----------------
__global__ __launch_bounds__(256) void embed_kernel(
    const int* __restrict__ tok, const float* __restrict__ emb,
    const float* __restrict__ pe, float* __restrict__ X, int total) {
  int i = blockIdx.x * 256 + threadIdx.x;
  if (i >= total) return;
  int d = i % D_MODEL;
  int bs = i / D_MODEL;
  int s = bs & (S_LEN - 1);
  int t = tok[bs];
  X[i] = emb[(size_t)t * D_MODEL + d] + pe[s * D_MODEL + d];
}

// ---------------- weight convert: fp32 -> fp16 ----------------
__global__ __launch_bounds__(256) void cvt_w_h(
    const float* __restrict__ W, unsigned short* __restrict__ H, int n4) {
  int i = blockIdx.x * 256 + threadIdx.x;
  if (i >= n4) return;
  float4 w = ((const float4*)W)[i];
  ushort4 h;
  h.x = f2h(w.x); h.y = f2h(w.y); h.z = f2h(w.z); h.w = f2h(w.w);
  ((ushort4*)H)[i] = h;
}

// ---------------- LayerNorm over D=768 -> fp16 output ----------------
__global__ __launch_bounds__(256) void ln_kernel(
    const float* __restrict__ X, const float* __restrict__ gam,
    const float* __restrict__ bet, unsigned short* __restrict__ Y) {
  __shared__ float scratch[4];
  const int row = blockIdx.x;
  const int tid = threadIdx.x;
  const float* xr = X + (size_t)row * D_MODEL;
  float v0 = xr[tid], v1 = xr[tid + 256], v2 = xr[tid + 512];
  float s = v0 + v1 + v2;
#pragma unroll
  for (int o = 32; o; o >>= 1) s += __shfl_xor(s, o, 64);
  if ((tid & 63) == 0) scratch[tid >> 6] = s;
  __syncthreads();
  float mean = (scratch[0] + scratch[1] + scratch[2] + scratch[3]) * (1.0f / 768.0f);
  __syncthreads();
  float d0 = v0 - mean, d1 = v1 - mean, d2 = v2 - mean;
  float ss = d0 * d0 + d1 * d1 + d2 * d2;
#pragma unroll
  for (int o = 32; o; o >>= 1) ss += __shfl_xor(ss, o, 64);
  if ((tid & 63) == 0) scratch[tid >> 6] = ss;
  __syncthreads();
  float var = (scratch[0] + scratch[1] + scratch[2] + scratch[3]) * (1.0f / 768.0f);
  float rstd = rsqrtf(var + 1e-5f);
  unsigned short* yr = Y + (size_t)row * D_MODEL;
  yr[tid]       = f2h(d0 * rstd * gam[tid]       + bet[tid]);
  yr[tid + 256] = f2h(d1 * rstd * gam[tid + 256] + bet[tid + 256]);
  yr[tid + 512] = f2h(d2 * rstd * gam[tid + 512] + bet[tid + 512]);
}

// ---------------- gemm128: 128x128 tile, BK=32, 4 waves, single-barrier 3-buffer --
// XCD chunk + 8x2 super-tile remap keeps per-XCD L2 working set ~2 MB.
// EPI 0: C_f16 = acc+bias   1: gelu   2: C_f32 += acc+bias (residual RMW)
template <int EPI>
__global__ __launch_bounds__(256) void gemm128(
    const unsigned short* __restrict__ A, const unsigned short* __restrict__ W,
    const float* __restrict__ bias, void* __restrict__ Cv,
    int N, int K, int NX) {
  __shared__ __align__(16) unsigned short SH[24576];  // 3 buffers x (A 8KB + B 8KB)
  const int tid = threadIdx.x;
  const int nwg = gridDim.x;
  const int wg = ((blockIdx.x & 7) * (nwg >> 3)) + (blockIdx.x >> 3);
  const int SX = NX >> 1;
  const int st = wg >> 4, w16 = wg & 15;
  const int ty = (st / SX) * 8 + (w16 >> 1);
  const int tx = (st % SX) * 2 + (w16 & 1);
  const int m0 = ty << 7, n0 = tx << 7;
  const int wave = tid >> 6, lane = tid & 63;
  const int wr = (wave >> 1) << 6, wc = (wave & 1) << 6;
  const int lq = lane >> 4, lr = lane & 15;
  const int rA0 = (wave << 5) + (lane >> 2);
  const int rA1 = rA0 + 16;
  const int sl = lane & 3;
  const size_t gA0 = (size_t)(m0 + rA0) * K + ((sl ^ ((rA0 >> 1) & 3)) << 3);
  const size_t gA1 = (size_t)(m0 + rA1) * K + ((sl ^ ((rA1 >> 1) & 3)) << 3);
  const size_t gB0 = (size_t)(n0 + rA0) * K + ((sl ^ ((rA0 >> 1) & 3)) << 3);
  const size_t gB1 = (size_t)(n0 + rA1) * K + ((sl ^ ((rA1 >> 1) & 3)) << 3);
  const int lws = wave << 10;

  const int nt = K >> 5;
  auto stage = [&](int buf, int t) {
    unsigned short* base = SH + (buf << 13);
    const int kk = t << 5;
    gload16(A + gA0 + kk, base + lws);
    gload16(A + gA1 + kk, base + lws + 512);
    gload16(W + gB0 + kk, base + 4096 + lws);
    gload16(W + gB1 + kk, base + 4096 + lws + 512);
  };
  stage(0, 0);
  stage(1, 1);

  f32x4 acc[4][4] = {};
  int cb = 0;                         // compute-buffer index (cycles 0,1,2)
  for (int t = 0; t < nt; ++t) {
    if (t + 1 < nt) {
      asm volatile("s_waitcnt vmcnt(4)" ::: "memory");   // tile t's 4 loads done
    } else {
      asm volatile("s_waitcnt vmcnt(0)" ::: "memory");
    }
    __builtin_amdgcn_s_barrier();                         // everyone's tile t ready
    __builtin_amdgcn_sched_barrier(0);
    const unsigned short* As = SH + (cb << 13);
    const unsigned short* Bs = As + 4096;
    f16x8 af[4], bq[4];
#pragma unroll
    for (int i = 0; i < 4; ++i) {
      int r = wr + (i << 4) + lr;
      af[i] = *(const f16x8*)&As[r * 32 + ((lq ^ ((r >> 1) & 3)) << 3)];
    }
#pragma unroll
    for (int j = 0; j < 4; ++j) {
      int r = wc + (j << 4) + lr;
      bq[j] = *(const f16x8*)&Bs[r * 32 + ((lq ^ ((r >> 1) & 3)) << 3)];
    }
    if (t + 2 < nt) {                 // stage overlaps the MFMA cluster
      int sb = cb + 2; if (sb >= 3) sb -= 3;
      stage(sb, t + 2);
    }
    __builtin_amdgcn_sched_barrier(0);                    // pin stage before MFMAs
    __builtin_amdgcn_s_setprio(1);
#pragma unroll
    for (int i = 0; i < 4; ++i)
#pragma unroll
      for (int j = 0; j < 4; ++j)
        acc[i][j] = __builtin_amdgcn_mfma_f32_16x16x32_f16(af[i], bq[j], acc[i][j], 0, 0, 0);
    __builtin_amdgcn_s_setprio(0);
    cb = (cb == 2) ? 0 : cb + 1;
  }
  // bias per j-fragment column
  float bval[4];
#pragma unroll
  for (int j = 0; j < 4; ++j) bval[j] = bias[n0 + wc + (j << 4) + lr];

  if (EPI == 2) {
    // residual RMW epilogue (fp32 C)
    float* C = (float*)Cv;
#pragma unroll
    for (int j = 0; j < 4; ++j) {
      const int gcol = n0 + wc + (j << 4) + lr;
#pragma unroll
      for (int i = 0; i < 4; ++i) {
        const int grow0 = m0 + wr + (i << 4) + (lq << 2);
#pragma unroll
        for (int r = 0; r < 4; ++r) {
          size_t off = (size_t)(grow0 + r) * N + gcol;
          C[off] += acc[i][j][r] + bval[j];
        }
      }
    }
    return;
  }

  unsigned short* C = (unsigned short*)Cv;
  __syncthreads();
  // repacked epilogue: two 64-row halves through LDS buffer 0, 16B/lane stores
#pragma unroll
  for (int hh = 0; hh < 2; ++hh) {
    if ((wave >> 1) == hh) {
#pragma unroll
      for (int i = 0; i < 4; ++i)
#pragma unroll
        for (int j = 0; j < 4; ++j) {
          const int colb = wc + (j << 4) + lr;
#pragma unroll
          for (int r = 0; r < 4; ++r) {
            const int rowl = (i << 4) + (lq << 2) + r;
            float v = acc[i][j][r] + bval[j];
            if (EPI == 1) v = gelu_exact(v);
            const int ch = (colb >> 3) ^ (rowl & 7);
            SH[rowl * 128 + (ch << 3) + (colb & 7)] = f2h(v);
          }
        }
    }
    __syncthreads();
#pragma unroll
    for (int it = 0; it < 4; ++it) {
      const int cid = tid + (it << 8);
      const int row = cid >> 4, ch = cid & 15;
      uint4 v8 = *(uint4*)&SH[row * 128 + ((ch ^ (row & 7)) << 3)];
      *(uint4*)&C[(size_t)(m0 + (hh << 6) + row) * N + n0 + (ch << 3)] = v8;
    }
    __syncthreads();
  }
}

// ---------------- banded attention: MFMA QK^T + softmax + MFMA PV (fp16) ---------
// grid (b, qtile): XCD = b. Vt slot swizzle = (d>>3)&7 (bijective in d-octet ->
// scatter writes spread across all 8 bank groups; reads stay 2-way/free).
__global__ __launch_bounds__(512) void attn_kernel(
    const unsigned short* __restrict__ qkv, const int* __restrict__ mask,
    unsigned short* __restrict__ attn_out, float* __restrict__ allw) {
  __shared__ __align__(16) unsigned short Ks[KB * 72];
  __shared__ __align__(16) unsigned short Vt[64 * 328];
  __shared__ __align__(16) unsigned short Qs[32 * 72];
  __shared__ __align__(16) unsigned short Ps[32 * 328];
  __shared__ __align__(16) float redmax[2][16][4];
  __shared__ __align__(16) float redsum[2][16][4];
  __shared__ int kvalid[KB];

  const int qt0 = blockIdx.y * QT;
  const int b = blockIdx.x;
  const int tid = threadIdx.x;
  const int w = tid >> 6, lane = tid & 63;
  const int lr = lane & 15, lg = lane >> 4;
  const int k0 = qt0 - 128;
  const int qh = w & 1, wq = w >> 1;
  const int nkt = (wq < 2) ? 5 : 4;

  for (int j = tid; j < KB; j += 512) {
    int key = k0 + j;
    kvalid[j] = (key >= 0 && key < S_LEN && mask[b * S_LEN + key] != 0) ? 1 : 0;
  }

  f32x4 pm[5] = {};
  const size_t rowbase = (size_t)(b * S_LEN) * 2304;
  const int qloc = lg << 2;
  const int qbase = (qh << 4) + qloc;

  for (int h = 0; h < NHEAD; ++h) {
    const int hoff = h << 6;
    if (tid < 256) {
      int r = tid >> 3, c = tid & 7;
      uint4 v = *(const uint4*)(qkv + rowbase + (size_t)(qt0 + r) * 2304 + hoff + (c << 3));
      *(uint4*)&Qs[r * 72 + ((c ^ (r & 7)) << 3)] = v;
    }
    for (int idx = tid; idx < 2304; idx += 512) {
      int r = idx >> 3, c = idx & 7;
      int key = k0 + r;
      uint4 kv = {0, 0, 0, 0}, vv = {0, 0, 0, 0};
      if ((unsigned)key < (unsigned)S_LEN) {
        const unsigned short* base = qkv + rowbase + (size_t)key * 2304 + hoff + (c << 3);
        kv = *(const uint4*)(base + 768);
        vv = *(const uint4*)(base + 1536);
      }
      *(uint4*)&Ks[r * 72 + ((c ^ (r & 7)) << 3)] = kv;
      const unsigned short* ve = (const unsigned short*)&vv;
      int jc = r >> 3, jw = r & 7;
#pragma unroll
      for (int e = 0; e < 8; ++e) {
        int d = (c << 3) + e;
        Vt[d * 328 + ((jc ^ ((d >> 3) & 7)) << 3) + jw] = ve[e];
      }
    }
    __syncthreads();

    f16x8 aq[2];
#pragma unroll
    for (int kc = 0; kc < 2; ++kc) {
      int r = (qh << 4) + lr;
      aq[kc] = *(f16x8*)&Qs[r * 72 + ((((kc << 2) + lg) ^ (r & 7)) << 3)];
    }
    f32x4 sc[5];
    __builtin_amdgcn_s_setprio(1);
#pragma unroll
    for (int t = 0; t < 5; ++t) {
      sc[t] = (f32x4){0.0f, 0.0f, 0.0f, 0.0f};
      if (t < nkt) {
        int r = ((wq + (t << 2)) << 4) + lr;
#pragma unroll
        for (int kc = 0; kc < 2; ++kc) {
          f16x8 bk = *(f16x8*)&Ks[r * 72 + ((((kc << 2) + lg) ^ (r & 7)) << 3)];
          sc[t] = __builtin_amdgcn_mfma_f32_16x16x32_f16(aq[kc], bk, sc[t], 0, 0, 0);
        }
      }
    }
    __builtin_amdgcn_s_setprio(0);
#pragma unroll
    for (int t = 0; t < 5; ++t) if (t < nkt) {
      int j = ((wq + (t << 2)) << 4) + lr;
      int okk = kvalid[j];
#pragma unroll
      for (int rg = 0; rg < 4; ++rg) {
        int q = qbase + rg;
        float s = sc[t][rg] * 0.125f;
        sc[t][rg] = (okk && j >= q && j <= q + 256) ? s : NEG_INF;
      }
    }
    float mx[4], zs[4];
#pragma unroll
    for (int rg = 0; rg < 4; ++rg) {
      float m = NEG_INF;
#pragma unroll
      for (int t = 0; t < 5; ++t) if (t < nkt) m = fmaxf(m, sc[t][rg]);
      mx[rg] = m;
    }
#pragma unroll
    for (int o = 1; o < 16; o <<= 1)
#pragma unroll
      for (int rg = 0; rg < 4; ++rg) mx[rg] = fmaxf(mx[rg], __shfl_xor(mx[rg], o, 64));
    if (lr == 0)
#pragma unroll
      for (int rg = 0; rg < 4; ++rg) redmax[qh][qloc + rg][wq] = mx[rg];
    __syncthreads();
#pragma unroll
    for (int rg = 0; rg < 4; ++rg) {
      f32x4 v = *(f32x4*)&redmax[qh][qloc + rg][0];
      mx[rg] = fmaxf(fmaxf(v[0], v[1]), fmaxf(v[2], v[3]));
      zs[rg] = 0.0f;
    }
#pragma unroll
    for (int t = 0; t < 5; ++t) if (t < nkt)
#pragma unroll
      for (int rg = 0; rg < 4; ++rg) {
        float e = expf(sc[t][rg] - mx[rg]);
        sc[t][rg] = e;
        zs[rg] += e;
      }
#pragma unroll
    for (int o = 1; o < 16; o <<= 1)
#pragma unroll
      for (int rg = 0; rg < 4; ++rg) zs[rg] += __shfl_xor(zs[rg], o, 64);
    if (lr == 0)
#pragma unroll
      for (int rg = 0; rg < 4; ++rg) redsum[qh][qloc + rg][wq] = zs[rg];
    __syncthreads();
#pragma unroll
    for (int rg = 0; rg < 4; ++rg) {
      f32x4 v = *(f32x4*)&redsum[qh][qloc + rg][0];
      zs[rg] = 1.0f / (v[0] + v[1] + v[2] + v[3]);
    }
#pragma unroll
    for (int t = 0; t < 5; ++t) if (t < nkt) {
      int j = ((wq + (t << 2)) << 4) + lr;
      int pc = j >> 3, pw = j & 7;
#pragma unroll
      for (int rg = 0; rg < 4; ++rg) {
        float p = sc[t][rg] * zs[rg];
        pm[t][rg] += p;
        int row = qbase + rg;
        Ps[row * 328 + ((pc ^ (row & 7)) << 3) + pw] = f2h(p);
      }
    }
    __syncthreads();
    {
      const int qt = w >> 2, dt = w & 3;
      const int ra = (qt << 4) + lr;
      const int rd = (dt << 4) + lr;
      f32x4 o4 = {0.0f, 0.0f, 0.0f, 0.0f};
      __builtin_amdgcn_s_setprio(1);
#pragma unroll
      for (int ks = 0; ks < 9; ++ks) {
        f16x8 pa = *(f16x8*)&Ps[ra * 328 + ((((ks << 2) + lg) ^ (ra & 7)) << 3)];
        f16x8 vb = *(f16x8*)&Vt[rd * 328 + ((((ks << 2) + lg) ^ ((rd >> 3) & 7)) << 3)];
        o4 = __builtin_amdgcn_mfma_f32_16x16x32_f16(pa, vb, o4, 0, 0, 0);
      }
      __builtin_amdgcn_s_setprio(0);
      unsigned short* op = attn_out +
          ((size_t)(b * S_LEN + qt0 + (qt << 4) + (lg << 2))) * D_MODEL + hoff + (dt << 4) + lr;
#pragma unroll
      for (int rg = 0; rg < 4; ++rg) op[(size_t)rg * D_MODEL] = f2h(o4[rg]);
    }
    __syncthreads();
  }

#pragma unroll
  for (int t = 0; t < 5; ++t) if (t < nkt) {
    int j = ((wq + (t << 2)) << 4) + lr;
    int key = k0 + j;
    if ((unsigned)key < (unsigned)S_LEN) {
      float* ap = allw + ((size_t)(b * S_LEN) + qt0 + qbase) * S_LEN + key;
#pragma unroll
      for (int rg = 0; rg < 4; ++rg) ap[(size_t)rg * S_LEN] = pm[t][rg] * (1.0f / 12.0f);
    }
  }
}

// ---------------- pooling stage 1: scores sc[b,s] = x·pool_w + pool_b ----------
__global__ __launch_bounds__(256) void pool_score(
    const float* __restrict__ X, const int* __restrict__ mask,
    const float* __restrict__ pool_w, const float* __restrict__ pool_b,
    float* __restrict__ sc) {
  const int tid = threadIdx.x;
  const int wave = tid >> 6, lane = tid & 63;
  const int row = blockIdx.x * 4 + wave;
  const float* xr = X + (size_t)row * D_MODEL;
  float acc = 0.0f;
#pragma unroll
  for (int c = 0; c < 3; ++c) {
    int d = (lane << 2) + (c << 8);
    float4 xv = *(const float4*)(xr + d);
    float4 wv = *(const float4*)(pool_w + d);
    acc += xv.x * wv.x + xv.y * wv.y + xv.z * wv.z + xv.w * wv.w;
  }
#pragma unroll
  for (int o = 32; o; o >>= 1) acc += __shfl_xor(acc, o, 64);
  if (lane == 0)
    sc[row] = (mask[row] == 0) ? NEG_INF : (acc + pool_b[0]);
}

// ---------------- pooling stage 2: softmax over S per batch (in-place) ---------
__global__ __launch_bounds__(256) void pool_softmax(float* __restrict__ sc) {
  __shared__ float scratch[4];
  __shared__ float buf[S_LEN];
  const int b = blockIdx.x;
  const int tid = threadIdx.x;
  float* sb = sc + b * S_LEN;
  float m = NEG_INF;
  for (int s = tid; s < S_LEN; s += 256) { buf[s] = sb[s]; m = fmaxf(m, buf[s]); }
#pragma unroll
  for (int o = 32; o; o >>= 1) m = fmaxf(m, __shfl_xor(m, o, 64));
  if ((tid & 63) == 0) scratch[tid >> 6] = m;
  __syncthreads();
  m = fmaxf(fmaxf(scratch[0], scratch[1]), fmaxf(scratch[2], scratch[3]));
  __syncthreads();
  float z = 0.0f;
  for (int s = tid; s < S_LEN; s += 256) { float e = expf(buf[s] - m); buf[s] = e; z += e; }
#pragma unroll
  for (int o = 32; o; o >>= 1) z += __shfl_xor(z, o, 64);
  if ((tid & 63) == 0) scratch[tid >> 6] = z;
  __syncthreads();
  float Z = scratch[0] + scratch[1] + scratch[2] + scratch[3];
  const float inv = 1.0f / Z;
  for (int s = tid; s < S_LEN; s += 256) sb[s] = buf[s] * inv;
}

// ---------------- pooling stage 3: partial weighted sums over s-chunks ---------
__global__ __launch_bounds__(256) void pool_sum(
    const float* __restrict__ X, const float* __restrict__ wgt,
    float* __restrict__ partial) {
  const int bx = blockIdx.x;            // dchunk*8 + schunk
  const int b = blockIdx.y;
  const int dchunk = bx >> 3, schunk = bx & 7;
  const int d = (dchunk << 8) + threadIdx.x;
  const int s0 = schunk << 7;
  const float* xb = X + ((size_t)(b << 10) + s0) * D_MODEL + d;
  const float* wb = wgt + (b << 10) + s0;
  float acc = 0.0f;
  for (int s = 0; s < 128; ++s) acc += wb[s] * xb[(size_t)s * D_MODEL];
  partial[((size_t)((b << 3) + schunk)) * D_MODEL + d] = acc;
}

// ---------------- classifier stage A: reduce partials, tanh, LN -> cbuf --------
__global__ __launch_bounds__(256) void cls_ln(
    const float* __restrict__ partial,
    const float* __restrict__ ln_s, const float* __restrict__ ln_b,
    float* __restrict__ cbuf_g) {
  const int b = blockIdx.x;
  const int tid = threadIdx.x;
  __shared__ float scratch[4];
  __shared__ __align__(16) float pbuf[D_MODEL];
  for (int d = tid; d < D_MODEL; d += 256) {
    float acc = 0.0f;
#pragma unroll
    for (int p = 0; p < 8; ++p) acc += partial[((size_t)((b << 3) + p)) * D_MODEL + d];
    pbuf[d] = tanhf(acc);
  }
  __syncthreads();
  float ls = 0.0f;
  for (int d = tid; d < D_MODEL; d += 256) ls += pbuf[d];
#pragma unroll
  for (int o = 32; o; o >>= 1) ls += __shfl_xor(ls, o, 64);
  if ((tid & 63) == 0) scratch[tid >> 6] = ls;
  __syncthreads();
  float mean = (scratch[0] + scratch[1] + scratch[2] + scratch[3]) * (1.0f / 768.0f);
  __syncthreads();
  float vs = 0.0f;
  for (int d = tid; d < D_MODEL; d += 256) { float dd = pbuf[d] - mean; vs += dd * dd; }
#pragma unroll
  for (int o = 32; o; o >>= 1) vs += __shfl_xor(vs, o, 64);
  if ((tid & 63) == 0) scratch[tid >> 6] = vs;
  __syncthreads();
  float var = (scratch[0] + scratch[1] + scratch[2] + scratch[3]) * (1.0f / 768.0f);
  float rstd = rsqrtf(var + 1e-5f);
  for (int d = tid; d < D_MODEL; d += 256)
    cbuf_g[b * D_MODEL + d] = (pbuf[d] - mean) * rstd * ln_s[d] + ln_b[d];
}

// ---------------- classifier stage B: c1[b,i] = tanh(cbuf·w1[i] + b1[i]) --------
__global__ __launch_bounds__(256) void cls_mlp1(
    const float* __restrict__ cbuf_g, const float* __restrict__ w1,
    const float* __restrict__ b1, float* __restrict__ c1_g) {
  const int tid = threadIdx.x;
  const int wave = tid >> 6, lane = tid & 63;
  const int i = blockIdx.x * 4 + wave;
  const int b = blockIdx.y;
  __shared__ __align__(16) float cb[D_MODEL];
  for (int d = tid; d < D_MODEL; d += 256) cb[d] = cbuf_g[b * D_MODEL + d];
  __syncthreads();
  const float* wr = w1 + (size_t)i * D_MODEL;
  float acc = 0.0f;
#pragma unroll
  for (int c = 0; c < 3; ++c) {
    int d = (lane << 2) + (c << 8);
    float4 wv = *(const float4*)(wr + d);
    float4 cv = *(const float4*)(&cb[d]);
    acc += wv.x * cv.x + wv.y * cv.y + wv.z * cv.z + wv.w * cv.w;
  }
#pragma unroll
  for (int o = 32; o; o >>= 1) acc += __shfl_xor(acc, o, 64);
  if (lane == 0) c1_g[b * D_MODEL + i] = tanhf(acc + b1[i]);
}

// ---------------- classifier stage C: logits ----------------
__global__ __launch_bounds__(256) void cls_logits(
    const float* __restrict__ c1_g, const float* __restrict__ w2,
    const float* __restrict__ b2, float* __restrict__ out) {
  const int b = blockIdx.x;
  const int tid = threadIdx.x;
  __shared__ float scratch[4];
#pragma unroll
  for (int jc = 0; jc < 2; ++jc) {
    float acc = 0.0f;
    for (int i = tid; i < D_MODEL; i += 256) acc += c1_g[b * D_MODEL + i] * w2[jc * D_MODEL + i];
#pragma unroll
    for (int o = 32; o; o >>= 1) acc += __shfl_xor(acc, o, 64);
    if ((tid & 63) == 0) scratch[tid >> 6] = acc;
    __syncthreads();
    if (tid == 0) out[b * 2 + jc] = scratch[0] + scratch[1] + scratch[2] + scratch[3] + b2[jc];
    __syncthreads();
  }
}

extern "C" void kernel_launch(void* const* d_in, const int* in_sizes, int n_in,
                              void* d_out, int out_size, void* d_ws, size_t ws_size,
                              hipStream_t stream) {
  const int*   tokens  = (const int*)d_in[0];
  const int*   mask    = (const int*)d_in[1];
  const float* emb     = (const float*)d_in[2];
  const float* in_w    = (const float*)d_in[3];
  const float* in_b    = (const float*)d_in[4];
  const float* out_w   = (const float*)d_in[5];
  const float* out_b   = (const float*)d_in[6];
  const float* ln1_s   = (const float*)d_in[7];
  const float* ln1_b   = (const float*)d_in[8];
  const float* ln2_s   = (const float*)d_in[9];
  const float* ln2_b   = (const float*)d_in[10];
  const float* ff_w1   = (const float*)d_in[11];
  const float* ff_b1   = (const float*)d_in[12];
  const float* ff_w2   = (const float*)d_in[13];
  const float* ff_b2   = (const float*)d_in[14];
  const float* pool_w  = (const float*)d_in[15];
  const float* pool_b  = (const float*)d_in[16];
  const float* cls_ln_s = (const float*)d_in[17];
  const float* cls_ln_b = (const float*)d_in[18];
  const float* cls_w1  = (const float*)d_in[19];
  const float* cls_b1  = (const float*)d_in[20];
  const float* cls_w2  = (const float*)d_in[21];
  const float* cls_b2  = (const float*)d_in[22];

  float* outp = (float*)d_out;
  float* ws = (float*)d_ws;
  const size_t XN = (size_t)8 * 1024 * 768;          // 6,291,456
  const size_t BIGU = (size_t)8192 * 3072;           // 25,165,824 ushorts
  float* x = ws;
  unsigned short* bigu = (unsigned short*)(ws + XN);             // fp16 qkv / gelu
  unsigned short* h_f16 = (unsigned short*)(ws + XN + BIGU / 2); // fp16 activations
  unsigned short* wall = h_f16 + XN;                             // fp16 weight arena
  unsigned short* wall_in  = wall;                               // 4*2304*768
  unsigned short* wall_out = wall + (size_t)7077888;             // 4*768*768
  unsigned short* wall_ff1 = wall + (size_t)9437184;             // 4*3072*768
  unsigned short* wall_ff2 = wall + (size_t)18874368;            // 4*768*3072
  float* clsbuf = (float*)(wall + (size_t)28311552);
  float* sc_ws = clsbuf;                                         // 8192 floats
  float* partial = clsbuf + 8192;                                // 49152 floats
  float* cbuf_ws = partial + 49152;                              // 6144 floats
  float* c1_ws = cbuf_ws + 6144;                                 // 6144 floats
  float* pe_ws = c1_ws + 6144;                                   // 786432 floats
  float* allw = outp + 16;

  hipMemsetAsync(d_out, 0, (size_t)out_size * sizeof(float), stream);

  // PE table + upfront weight conversion (all layers)
  pe_init<<<3072, 256, 0, stream>>>(pe_ws);
  cvt_w_h<<<6912, 256, 0, stream>>>(in_w,  wall_in,  1769472);
  cvt_w_h<<<2304, 256, 0, stream>>>(out_w, wall_out,  589824);
  cvt_w_h<<<9216, 256, 0, stream>>>(ff_w1, wall_ff1, 2359296);
  cvt_w_h<<<9216, 256, 0, stream>>>(ff_w2, wall_ff2, 2359296);

  const int total = (int)XN;
  embed_kernel<<<(total + 255) / 256, 256, 0, stream>>>(tokens, emb, pe_ws, x, total);

  for (int l = 0; l < 4; ++l) {
    ln_kernel<<<8192, 256, 0, stream>>>(x, ln1_s + l * 768, ln1_b + l * 768, h_f16);
    gemm128<0><<<1152, 256, 0, stream>>>(h_f16, wall_in + (size_t)l * 1769472,
                                         in_b + l * 2304, bigu, 2304, 768, 18);
    attn_kernel<<<dim3(8, S_LEN / QT), 512, 0, stream>>>(bigu, mask, h_f16,
                                                         allw + (size_t)l * 8 * 1024 * 1024);
    gemm128<2><<<384, 256, 0, stream>>>(h_f16, wall_out + (size_t)l * 589824,
                                        out_b + l * 768, x, 768, 768, 6);
    ln_kernel<<<8192, 256, 0, stream>>>(x, ln2_s + l * 768, ln2_b + l * 768, h_f16);
    gemm128<1><<<1536, 256, 0, stream>>>(h_f16, wall_ff1 + (size_t)l * 2359296,
                                         ff_b1 + l * 3072, bigu, 3072, 768, 24);
    gemm128<2><<<384, 256, 0, stream>>>(bigu, wall_ff2 + (size_t)l * 2359296,
                                        ff_b2 + l * 768, x, 768, 3072, 6);
  }

  pool_score<<<2048, 256, 0, stream>>>(x, mask, pool_w, pool_b, sc_ws);
  pool_softmax<<<8, 256, 0, stream>>>(sc_ws);
  pool_sum<<<dim3(24, 8), 256, 0, stream>>>(x, sc_ws, partial);
  cls_ln<<<8, 256, 0, stream>>>(partial, cls_ln_s, cls_ln_b, cbuf_ws);
  cls_mlp1<<<dim3(192, 8), 256, 0, stream>>>(cbuf_ws, cls_w1, cls_b1, c1_ws);
  cls_logits<<<8, 256, 0, stream>>>(c1_ws, cls_w2, cls_b2, outp);
}

// Round 22
// 1329.389 us; speedup vs baseline: 1.0313x; 1.0132x over previous
//
#include <hip/hip_runtime.h>
#include <math.h>

#define S_LEN 1024
#define D_MODEL 768
#define NHEAD 12
#define NEG_INF -3.4028234663852886e38f

#define QT 32           // queries per attention block
#define KB 288          // key band per block = QT + 2*128

typedef _Float16 f16x8 __attribute__((ext_vector_type(8)));
typedef __attribute__((ext_vector_type(4))) float f32x4;

typedef const __attribute__((address_space(1))) unsigned int ga_u32;
typedef __attribute__((address_space(3))) unsigned int ls_u32;
__device__ __forceinline__ void gload16(const void* g, void* l) {
  __builtin_amdgcn_global_load_lds((ga_u32*)g, (ls_u32*)l, 16, 0, 0);
}

__device__ __forceinline__ float gelu_exact(float v) {
  return 0.5f * v * (1.0f + erff(v * 0.7071067811865475f));
}
__device__ __forceinline__ unsigned short f2h(float f) {
  union { _Float16 h; unsigned short u; } x; x.h = (_Float16)f; return x.u;
}

// ---------------- PE table init: pe[s][d], 1024x768 ----------------
__global__ __launch_bounds__(256) void pe_init(float* __restrict__ pe) {
  int i = blockIdx.x * 256 + threadIdx.x;
  if (i >= S_LEN * D_MODEL) return;
  int d = i % D_MODEL;
  int s = i / D_MODEL;
  float div = expf((float)(d & ~1) * (-9.210340371976184f / 768.0f));
  float ang = (float)s * div;
  pe[i] = (d & 1) ? cosf(ang) : sinf(ang);
}

// ---------------- embedding + PE table add (float4) ----------------
__global__ __launch_bounds__(256) void embed_kernel(
    const int* __restrict__ tok, const float* __restrict__ emb,
    const float* __restrict__ pe, float* __restrict__ X, int total4) {
  int i = blockIdx.x * 256 + threadIdx.x;
  if (i >= total4) return;
  int d4 = i % 192;
  int bs = i / 192;
  int s = bs & (S_LEN - 1);
  int t = tok[bs];
  float4 e = ((const float4*)emb)[(size_t)t * 192 + d4];
  float4 p = ((const float4*)pe)[(size_t)s * 192 + d4];
  float4 o; o.x = e.x + p.x; o.y = e.y + p.y; o.z = e.z + p.z; o.w = e.w + p.w;
  ((float4*)X)[i] = o;
}

// ---------------- weight convert: fp32 -> fp16 ----------------
__global__ __launch_bounds__(256) void cvt_w_h(
    const float* __restrict__ W, unsigned short* __restrict__ H, int n4) {
  int i = blockIdx.x * 256 + threadIdx.x;
  if (i >= n4) return;
  float4 w = ((const float4*)W)[i];
  ushort4 h;
  h.x = f2h(w.x); h.y = f2h(w.y); h.z = f2h(w.z); h.w = f2h(w.w);
  ((ushort4*)H)[i] = h;
}

// ---------------- LayerNorm: one wave per row, float4 loads, no LDS/barriers ----
__global__ __launch_bounds__(256) void ln_kernel(
    const float* __restrict__ X, const float* __restrict__ gam,
    const float* __restrict__ bet, unsigned short* __restrict__ Y) {
  const int tid = threadIdx.x;
  const int wave = tid >> 6, lane = tid & 63;
  const int row = blockIdx.x * 4 + wave;
  const float* xr = X + (size_t)row * D_MODEL;
  float4 v[3];
  float s = 0.0f;
#pragma unroll
  for (int c = 0; c < 3; ++c) {
    v[c] = *(const float4*)(xr + (lane << 2) + (c << 8));
    s += v[c].x + v[c].y + v[c].z + v[c].w;
  }
#pragma unroll
  for (int o = 32; o; o >>= 1) s += __shfl_xor(s, o, 64);
  const float mean = s * (1.0f / 768.0f);
  float ss = 0.0f;
#pragma unroll
  for (int c = 0; c < 3; ++c) {
    float d0 = v[c].x - mean, d1 = v[c].y - mean;
    float d2 = v[c].z - mean, d3 = v[c].w - mean;
    ss += d0 * d0 + d1 * d1 + d2 * d2 + d3 * d3;
  }
#pragma unroll
  for (int o = 32; o; o >>= 1) ss += __shfl_xor(ss, o, 64);
  const float rstd = rsqrtf(ss * (1.0f / 768.0f) + 1e-5f);
  unsigned short* yr = Y + (size_t)row * D_MODEL;
#pragma unroll
  for (int c = 0; c < 3; ++c) {
    const int d = (lane << 2) + (c << 8);
    float4 g = *(const float4*)(gam + d);
    float4 bb = *(const float4*)(bet + d);
    ushort4 o4;
    o4.x = f2h((v[c].x - mean) * rstd * g.x + bb.x);
    o4.y = f2h((v[c].y - mean) * rstd * g.y + bb.y);
    o4.z = f2h((v[c].z - mean) * rstd * g.z + bb.z);
    o4.w = f2h((v[c].w - mean) * rstd * g.w + bb.w);
    *(ushort4*)(yr + d) = o4;
  }
}

// ---------------- gemm128: 128x128 tile, BK=32, 4 waves, single-barrier 3-buffer --
// XCD chunk + 8x2 super-tile remap keeps per-XCD L2 working set ~2 MB.
// EPI 0: C_f16 = acc+bias   1: gelu   2: C_f32 += acc+bias (residual RMW)
template <int EPI>
__global__ __launch_bounds__(256) void gemm128(
    const unsigned short* __restrict__ A, const unsigned short* __restrict__ W,
    const float* __restrict__ bias, void* __restrict__ Cv,
    int N, int K, int NX) {
  __shared__ __align__(16) unsigned short SH[24576];  // 3 buffers x (A 8KB + B 8KB)
  const int tid = threadIdx.x;
  const int nwg = gridDim.x;
  const int wg = ((blockIdx.x & 7) * (nwg >> 3)) + (blockIdx.x >> 3);
  const int SX = NX >> 1;
  const int st = wg >> 4, w16 = wg & 15;
  const int ty = (st / SX) * 8 + (w16 >> 1);
  const int tx = (st % SX) * 2 + (w16 & 1);
  const int m0 = ty << 7, n0 = tx << 7;
  const int wave = tid >> 6, lane = tid & 63;
  const int wr = (wave >> 1) << 6, wc = (wave & 1) << 6;
  const int lq = lane >> 4, lr = lane & 15;
  const int rA0 = (wave << 5) + (lane >> 2);
  const int rA1 = rA0 + 16;
  const int sl = lane & 3;
  const size_t gA0 = (size_t)(m0 + rA0) * K + ((sl ^ ((rA0 >> 1) & 3)) << 3);
  const size_t gA1 = (size_t)(m0 + rA1) * K + ((sl ^ ((rA1 >> 1) & 3)) << 3);
  const size_t gB0 = (size_t)(n0 + rA0) * K + ((sl ^ ((rA0 >> 1) & 3)) << 3);
  const size_t gB1 = (size_t)(n0 + rA1) * K + ((sl ^ ((rA1 >> 1) & 3)) << 3);
  const int lws = wave << 10;

  const int nt = K >> 5;
  auto stage = [&](int buf, int t) {
    unsigned short* base = SH + (buf << 13);
    const int kk = t << 5;
    gload16(A + gA0 + kk, base + lws);
    gload16(A + gA1 + kk, base + lws + 512);
    gload16(W + gB0 + kk, base + 4096 + lws);
    gload16(W + gB1 + kk, base + 4096 + lws + 512);
  };
  stage(0, 0);
  stage(1, 1);

  f32x4 acc[4][4] = {};
  int cb = 0;                         // compute-buffer index (cycles 0,1,2)
  for (int t = 0; t < nt; ++t) {
    if (t + 1 < nt) {
      asm volatile("s_waitcnt vmcnt(4)" ::: "memory");   // tile t's 4 loads done
    } else {
      asm volatile("s_waitcnt vmcnt(0)" ::: "memory");
    }
    __builtin_amdgcn_s_barrier();                         // everyone's tile t ready
    __builtin_amdgcn_sched_barrier(0);
    const unsigned short* As = SH + (cb << 13);
    const unsigned short* Bs = As + 4096;
    f16x8 af[4], bq[4];
#pragma unroll
    for (int i = 0; i < 4; ++i) {
      int r = wr + (i << 4) + lr;
      af[i] = *(const f16x8*)&As[r * 32 + ((lq ^ ((r >> 1) & 3)) << 3)];
    }
#pragma unroll
    for (int j = 0; j < 4; ++j) {
      int r = wc + (j << 4) + lr;
      bq[j] = *(const f16x8*)&Bs[r * 32 + ((lq ^ ((r >> 1) & 3)) << 3)];
    }
    if (t + 2 < nt) {                 // stage overlaps the MFMA cluster
      int sb = cb + 2; if (sb >= 3) sb -= 3;
      stage(sb, t + 2);
    }
    __builtin_amdgcn_sched_barrier(0);                    // pin stage before MFMAs
    __builtin_amdgcn_s_setprio(1);
#pragma unroll
    for (int i = 0; i < 4; ++i)
#pragma unroll
      for (int j = 0; j < 4; ++j)
        acc[i][j] = __builtin_amdgcn_mfma_f32_16x16x32_f16(af[i], bq[j], acc[i][j], 0, 0, 0);
    __builtin_amdgcn_s_setprio(0);
    cb = (cb == 2) ? 0 : cb + 1;
  }
  // bias per j-fragment column
  float bval[4];
#pragma unroll
  for (int j = 0; j < 4; ++j) bval[j] = bias[n0 + wc + (j << 4) + lr];

  if (EPI == 2) {
    // residual RMW epilogue (fp32 C)
    float* C = (float*)Cv;
#pragma unroll
    for (int j = 0; j < 4; ++j) {
      const int gcol = n0 + wc + (j << 4) + lr;
#pragma unroll
      for (int i = 0; i < 4; ++i) {
        const int grow0 = m0 + wr + (i << 4) + (lq << 2);
#pragma unroll
        for (int r = 0; r < 4; ++r) {
          size_t off = (size_t)(grow0 + r) * N + gcol;
          C[off] += acc[i][j][r] + bval[j];
        }
      }
    }
    return;
  }

  unsigned short* C = (unsigned short*)Cv;
  __syncthreads();
  // repacked epilogue: two 64-row halves through LDS buffer 0, 16B/lane stores
#pragma unroll
  for (int hh = 0; hh < 2; ++hh) {
    if ((wave >> 1) == hh) {
#pragma unroll
      for (int i = 0; i < 4; ++i)
#pragma unroll
        for (int j = 0; j < 4; ++j) {
          const int colb = wc + (j << 4) + lr;
#pragma unroll
          for (int r = 0; r < 4; ++r) {
            const int rowl = (i << 4) + (lq << 2) + r;
            float v = acc[i][j][r] + bval[j];
            if (EPI == 1) v = gelu_exact(v);
            const int ch = (colb >> 3) ^ (rowl & 7);
            SH[rowl * 128 + (ch << 3) + (colb & 7)] = f2h(v);
          }
        }
    }
    __syncthreads();
#pragma unroll
    for (int it = 0; it < 4; ++it) {
      const int cid = tid + (it << 8);
      const int row = cid >> 4, ch = cid & 15;
      uint4 v8 = *(uint4*)&SH[row * 128 + ((ch ^ (row & 7)) << 3)];
      *(uint4*)&C[(size_t)(m0 + (hh << 6) + row) * N + n0 + (ch << 3)] = v8;
    }
    __syncthreads();
  }
}

// ---------------- banded attention: MFMA QK^T + softmax + MFMA PV (fp16) ---------
// grid (b, qtile): XCD = b. Vt slot swizzle = (d>>3)&7 (bijective in d-octet ->
// scatter writes spread across all 8 bank groups; reads stay 2-way/free).
__global__ __launch_bounds__(512) void attn_kernel(
    const unsigned short* __restrict__ qkv, const int* __restrict__ mask,
    unsigned short* __restrict__ attn_out, float* __restrict__ allw) {
  __shared__ __align__(16) unsigned short Ks[KB * 72];
  __shared__ __align__(16) unsigned short Vt[64 * 328];
  __shared__ __align__(16) unsigned short Qs[32 * 72];
  __shared__ __align__(16) unsigned short Ps[32 * 328];
  __shared__ __align__(16) float redmax[2][16][4];
  __shared__ __align__(16) float redsum[2][16][4];
  __shared__ int kvalid[KB];

  const int qt0 = blockIdx.y * QT;
  const int b = blockIdx.x;
  const int tid = threadIdx.x;
  const int w = tid >> 6, lane = tid & 63;
  const int lr = lane & 15, lg = lane >> 4;
  const int k0 = qt0 - 128;
  const int qh = w & 1, wq = w >> 1;
  const int nkt = (wq < 2) ? 5 : 4;

  for (int j = tid; j < KB; j += 512) {
    int key = k0 + j;
    kvalid[j] = (key >= 0 && key < S_LEN && mask[b * S_LEN + key] != 0) ? 1 : 0;
  }

  f32x4 pm[5] = {};
  const size_t rowbase = (size_t)(b * S_LEN) * 2304;
  const int qloc = lg << 2;
  const int qbase = (qh << 4) + qloc;

  for (int h = 0; h < NHEAD; ++h) {
    const int hoff = h << 6;
    if (tid < 256) {
      int r = tid >> 3, c = tid & 7;
      uint4 v = *(const uint4*)(qkv + rowbase + (size_t)(qt0 + r) * 2304 + hoff + (c << 3));
      *(uint4*)&Qs[r * 72 + ((c ^ (r & 7)) << 3)] = v;
    }
    for (int idx = tid; idx < 2304; idx += 512) {
      int r = idx >> 3, c = idx & 7;
      int key = k0 + r;
      uint4 kv = {0, 0, 0, 0}, vv = {0, 0, 0, 0};
      if ((unsigned)key < (unsigned)S_LEN) {
        const unsigned short* base = qkv + rowbase + (size_t)key * 2304 + hoff + (c << 3);
        kv = *(const uint4*)(base + 768);
        vv = *(const uint4*)(base + 1536);
      }
      *(uint4*)&Ks[r * 72 + ((c ^ (r & 7)) << 3)] = kv;
      const unsigned short* ve = (const unsigned short*)&vv;
      int jc = r >> 3, jw = r & 7;
#pragma unroll
      for (int e = 0; e < 8; ++e) {
        int d = (c << 3) + e;
        Vt[d * 328 + ((jc ^ ((d >> 3) & 7)) << 3) + jw] = ve[e];
      }
    }
    __syncthreads();

    f16x8 aq[2];
#pragma unroll
    for (int kc = 0; kc < 2; ++kc) {
      int r = (qh << 4) + lr;
      aq[kc] = *(f16x8*)&Qs[r * 72 + ((((kc << 2) + lg) ^ (r & 7)) << 3)];
    }
    f32x4 sc[5];
    __builtin_amdgcn_s_setprio(1);
#pragma unroll
    for (int t = 0; t < 5; ++t) {
      sc[t] = (f32x4){0.0f, 0.0f, 0.0f, 0.0f};
      if (t < nkt) {
        int r = ((wq + (t << 2)) << 4) + lr;
#pragma unroll
        for (int kc = 0; kc < 2; ++kc) {
          f16x8 bk = *(f16x8*)&Ks[r * 72 + ((((kc << 2) + lg) ^ (r & 7)) << 3)];
          sc[t] = __builtin_amdgcn_mfma_f32_16x16x32_f16(aq[kc], bk, sc[t], 0, 0, 0);
        }
      }
    }
    __builtin_amdgcn_s_setprio(0);
#pragma unroll
    for (int t = 0; t < 5; ++t) if (t < nkt) {
      int j = ((wq + (t << 2)) << 4) + lr;
      int okk = kvalid[j];
#pragma unroll
      for (int rg = 0; rg < 4; ++rg) {
        int q = qbase + rg;
        float s = sc[t][rg] * 0.125f;
        sc[t][rg] = (okk && j >= q && j <= q + 256) ? s : NEG_INF;
      }
    }
    float mx[4], zs[4];
#pragma unroll
    for (int rg = 0; rg < 4; ++rg) {
      float m = NEG_INF;
#pragma unroll
      for (int t = 0; t < 5; ++t) if (t < nkt) m = fmaxf(m, sc[t][rg]);
      mx[rg] = m;
    }
#pragma unroll
    for (int o = 1; o < 16; o <<= 1)
#pragma unroll
      for (int rg = 0; rg < 4; ++rg) mx[rg] = fmaxf(mx[rg], __shfl_xor(mx[rg], o, 64));
    if (lr == 0)
#pragma unroll
      for (int rg = 0; rg < 4; ++rg) redmax[qh][qloc + rg][wq] = mx[rg];
    __syncthreads();
#pragma unroll
    for (int rg = 0; rg < 4; ++rg) {
      f32x4 v = *(f32x4*)&redmax[qh][qloc + rg][0];
      mx[rg] = fmaxf(fmaxf(v[0], v[1]), fmaxf(v[2], v[3]));
      zs[rg] = 0.0f;
    }
#pragma unroll
    for (int t = 0; t < 5; ++t) if (t < nkt)
#pragma unroll
      for (int rg = 0; rg < 4; ++rg) {
        float e = expf(sc[t][rg] - mx[rg]);
        sc[t][rg] = e;
        zs[rg] += e;
      }
#pragma unroll
    for (int o = 1; o < 16; o <<= 1)
#pragma unroll
      for (int rg = 0; rg < 4; ++rg) zs[rg] += __shfl_xor(zs[rg], o, 64);
    if (lr == 0)
#pragma unroll
      for (int rg = 0; rg < 4; ++rg) redsum[qh][qloc + rg][wq] = zs[rg];
    __syncthreads();
#pragma unroll
    for (int rg = 0; rg < 4; ++rg) {
      f32x4 v = *(f32x4*)&redsum[qh][qloc + rg][0];
      zs[rg] = 1.0f / (v[0] + v[1] + v[2] + v[3]);
    }
#pragma unroll
    for (int t = 0; t < 5; ++t) if (t < nkt) {
      int j = ((wq + (t << 2)) << 4) + lr;
      int pc = j >> 3, pw = j & 7;
#pragma unroll
      for (int rg = 0; rg < 4; ++rg) {
        float p = sc[t][rg] * zs[rg];
        pm[t][rg] += p;
        int row = qbase + rg;
        Ps[row * 328 + ((pc ^ (row & 7)) << 3) + pw] = f2h(p);
      }
    }
    __syncthreads();
    {
      const int qt = w >> 2, dt = w & 3;
      const int ra = (qt << 4) + lr;
      const int rd = (dt << 4) + lr;
      f32x4 o4 = {0.0f, 0.0f, 0.0f, 0.0f};
      __builtin_amdgcn_s_setprio(1);
#pragma unroll
      for (int ks = 0; ks < 9; ++ks) {
        f16x8 pa = *(f16x8*)&Ps[ra * 328 + ((((ks << 2) + lg) ^ (ra & 7)) << 3)];
        f16x8 vb = *(f16x8*)&Vt[rd * 328 + ((((ks << 2) + lg) ^ ((rd >> 3) & 7)) << 3)];
        o4 = __builtin_amdgcn_mfma_f32_16x16x32_f16(pa, vb, o4, 0, 0, 0);
      }
      __builtin_amdgcn_s_setprio(0);
      unsigned short* op = attn_out +
          ((size_t)(b * S_LEN + qt0 + (qt << 4) + (lg << 2))) * D_MODEL + hoff + (dt << 4) + lr;
#pragma unroll
      for (int rg = 0; rg < 4; ++rg) op[(size_t)rg * D_MODEL] = f2h(o4[rg]);
    }
    __syncthreads();
  }

#pragma unroll
  for (int t = 0; t < 5; ++t) if (t < nkt) {
    int j = ((wq + (t << 2)) << 4) + lr;
    int key = k0 + j;
    if ((unsigned)key < (unsigned)S_LEN) {
      float* ap = allw + ((size_t)(b * S_LEN) + qt0 + qbase) * S_LEN + key;
#pragma unroll
      for (int rg = 0; rg < 4; ++rg) ap[(size_t)rg * S_LEN] = pm[t][rg] * (1.0f / 12.0f);
    }
  }
}

// ---------------- pooling stage 1: scores sc[b,s] = x·pool_w + pool_b ----------
__global__ __launch_bounds__(256) void pool_score(
    const float* __restrict__ X, const int* __restrict__ mask,
    const float* __restrict__ pool_w, const float* __restrict__ pool_b,
    float* __restrict__ sc) {
  const int tid = threadIdx.x;
  const int wave = tid >> 6, lane = tid & 63;
  const int row = blockIdx.x * 4 + wave;
  const float* xr = X + (size_t)row * D_MODEL;
  float acc = 0.0f;
#pragma unroll
  for (int c = 0; c < 3; ++c) {
    int d = (lane << 2) + (c << 8);
    float4 xv = *(const float4*)(xr + d);
    float4 wv = *(const float4*)(pool_w + d);
    acc += xv.x * wv.x + xv.y * wv.y + xv.z * wv.z + xv.w * wv.w;
  }
#pragma unroll
  for (int o = 32; o; o >>= 1) acc += __shfl_xor(acc, o, 64);
  if (lane == 0)
    sc[row] = (mask[row] == 0) ? NEG_INF : (acc + pool_b[0]);
}

// ---------------- pooling stage 2: softmax over S per batch (in-place) ---------
__global__ __launch_bounds__(256) void pool_softmax(float* __restrict__ sc) {
  __shared__ float scratch[4];
  __shared__ float buf[S_LEN];
  const int b = blockIdx.x;
  const int tid = threadIdx.x;
  float* sb = sc + b * S_LEN;
  float m = NEG_INF;
  for (int s = tid; s < S_LEN; s += 256) { buf[s] = sb[s]; m = fmaxf(m, buf[s]); }
#pragma unroll
  for (int o = 32; o; o >>= 1) m = fmaxf(m, __shfl_xor(m, o, 64));
  if ((tid & 63) == 0) scratch[tid >> 6] = m;
  __syncthreads();
  m = fmaxf(fmaxf(scratch[0], scratch[1]), fmaxf(scratch[2], scratch[3]));
  __syncthreads();
  float z = 0.0f;
  for (int s = tid; s < S_LEN; s += 256) { float e = expf(buf[s] - m); buf[s] = e; z += e; }
#pragma unroll
  for (int o = 32; o; o >>= 1) z += __shfl_xor(z, o, 64);
  if ((tid & 63) == 0) scratch[tid >> 6] = z;
  __syncthreads();
  float Z = scratch[0] + scratch[1] + scratch[2] + scratch[3];
  const float inv = 1.0f / Z;
  for (int s = tid; s < S_LEN; s += 256) sb[s] = buf[s] * inv;
}

// ---------------- pooling stage 3: partial weighted sums over s-chunks ---------
__global__ __launch_bounds__(256) void pool_sum(
    const float* __restrict__ X, const float* __restrict__ wgt,
    float* __restrict__ partial) {
  const int bx = blockIdx.x;            // dchunk*8 + schunk
  const int b = blockIdx.y;
  const int dchunk = bx >> 3, schunk = bx & 7;
  const int d = (dchunk << 8) + threadIdx.x;
  const int s0 = schunk << 7;
  const float* xb = X + ((size_t)(b << 10) + s0) * D_MODEL + d;
  const float* wb = wgt + (b << 10) + s0;
  float acc = 0.0f;
  for (int s = 0; s < 128; ++s) acc += wb[s] * xb[(size_t)s * D_MODEL];
  partial[((size_t)((b << 3) + schunk)) * D_MODEL + d] = acc;
}

// ---------------- classifier stage A: reduce partials, tanh, LN -> cbuf --------
__global__ __launch_bounds__(256) void cls_ln(
    const float* __restrict__ partial,
    const float* __restrict__ ln_s, const float* __restrict__ ln_b,
    float* __restrict__ cbuf_g) {
  const int b = blockIdx.x;
  const int tid = threadIdx.x;
  __shared__ float scratch[4];
  __shared__ __align__(16) float pbuf[D_MODEL];
  for (int d = tid; d < D_MODEL; d += 256) {
    float acc = 0.0f;
#pragma unroll
    for (int p = 0; p < 8; ++p) acc += partial[((size_t)((b << 3) + p)) * D_MODEL + d];
    pbuf[d] = tanhf(acc);
  }
  __syncthreads();
  float ls = 0.0f;
  for (int d = tid; d < D_MODEL; d += 256) ls += pbuf[d];
#pragma unroll
  for (int o = 32; o; o >>= 1) ls += __shfl_xor(ls, o, 64);
  if ((tid & 63) == 0) scratch[tid >> 6] = ls;
  __syncthreads();
  float mean = (scratch[0] + scratch[1] + scratch[2] + scratch[3]) * (1.0f / 768.0f);
  __syncthreads();
  float vs = 0.0f;
  for (int d = tid; d < D_MODEL; d += 256) { float dd = pbuf[d] - mean; vs += dd * dd; }
#pragma unroll
  for (int o = 32; o; o >>= 1) vs += __shfl_xor(vs, o, 64);
  if ((tid & 63) == 0) scratch[tid >> 6] = vs;
  __syncthreads();
  float var = (scratch[0] + scratch[1] + scratch[2] + scratch[3]) * (1.0f / 768.0f);
  float rstd = rsqrtf(var + 1e-5f);
  for (int d = tid; d < D_MODEL; d += 256)
    cbuf_g[b * D_MODEL + d] = (pbuf[d] - mean) * rstd * ln_s[d] + ln_b[d];
}

// ---------------- classifier stage B: c1[b,i] = tanh(cbuf·w1[i] + b1[i]) --------
__global__ __launch_bounds__(256) void cls_mlp1(
    const float* __restrict__ cbuf_g, const float* __restrict__ w1,
    const float* __restrict__ b1, float* __restrict__ c1_g) {
  const int tid = threadIdx.x;
  const int wave = tid >> 6, lane = tid & 63;
  const int i = blockIdx.x * 4 + wave;
  const int b = blockIdx.y;
  __shared__ __align__(16) float cb[D_MODEL];
  for (int d = tid; d < D_MODEL; d += 256) cb[d] = cbuf_g[b * D_MODEL + d];
  __syncthreads();
  const float* wr = w1 + (size_t)i * D_MODEL;
  float acc = 0.0f;
#pragma unroll
  for (int c = 0; c < 3; ++c) {
    int d = (lane << 2) + (c << 8);
    float4 wv = *(const float4*)(wr + d);
    float4 cv = *(const float4*)(&cb[d]);
    acc += wv.x * cv.x + wv.y * cv.y + wv.z * cv.z + wv.w * cv.w;
  }
#pragma unroll
  for (int o = 32; o; o >>= 1) acc += __shfl_xor(acc, o, 64);
  if (lane == 0) c1_g[b * D_MODEL + i] = tanhf(acc + b1[i]);
}

// ---------------- classifier stage C: logits ----------------
__global__ __launch_bounds__(256) void cls_logits(
    const float* __restrict__ c1_g, const float* __restrict__ w2,
    const float* __restrict__ b2, float* __restrict__ out) {
  const int b = blockIdx.x;
  const int tid = threadIdx.x;
  __shared__ float scratch[4];
#pragma unroll
  for (int jc = 0; jc < 2; ++jc) {
    float acc = 0.0f;
    for (int i = tid; i < D_MODEL; i += 256) acc += c1_g[b * D_MODEL + i] * w2[jc * D_MODEL + i];
#pragma unroll
    for (int o = 32; o; o >>= 1) acc += __shfl_xor(acc, o, 64);
    if ((tid & 63) == 0) scratch[tid >> 6] = acc;
    __syncthreads();
    if (tid == 0) out[b * 2 + jc] = scratch[0] + scratch[1] + scratch[2] + scratch[3] + b2[jc];
    __syncthreads();
  }
}

extern "C" void kernel_launch(void* const* d_in, const int* in_sizes, int n_in,
                              void* d_out, int out_size, void* d_ws, size_t ws_size,
                              hipStream_t stream) {
  const int*   tokens  = (const int*)d_in[0];
  const int*   mask    = (const int*)d_in[1];
  const float* emb     = (const float*)d_in[2];
  const float* in_w    = (const float*)d_in[3];
  const float* in_b    = (const float*)d_in[4];
  const float* out_w   = (const float*)d_in[5];
  const float* out_b   = (const float*)d_in[6];
  const float* ln1_s   = (const float*)d_in[7];
  const float* ln1_b   = (const float*)d_in[8];
  const float* ln2_s   = (const float*)d_in[9];
  const float* ln2_b   = (const float*)d_in[10];
  const float* ff_w1   = (const float*)d_in[11];
  const float* ff_b1   = (const float*)d_in[12];
  const float* ff_w2   = (const float*)d_in[13];
  const float* ff_b2   = (const float*)d_in[14];
  const float* pool_w  = (const float*)d_in[15];
  const float* pool_b  = (const float*)d_in[16];
  const float* cls_ln_s = (const float*)d_in[17];
  const float* cls_ln_b = (const float*)d_in[18];
  const float* cls_w1  = (const float*)d_in[19];
  const float* cls_b1  = (const float*)d_in[20];
  const float* cls_w2  = (const float*)d_in[21];
  const float* cls_b2  = (const float*)d_in[22];

  float* outp = (float*)d_out;
  float* ws = (float*)d_ws;
  const size_t XN = (size_t)8 * 1024 * 768;          // 6,291,456
  const size_t BIGU = (size_t)8192 * 3072;           // 25,165,824 ushorts
  float* x = ws;
  unsigned short* bigu = (unsigned short*)(ws + XN);             // fp16 qkv / gelu
  unsigned short* h_f16 = (unsigned short*)(ws + XN + BIGU / 2); // fp16 activations
  unsigned short* wall = h_f16 + XN;                             // fp16 weight arena
  unsigned short* wall_in  = wall;                               // 4*2304*768
  unsigned short* wall_out = wall + (size_t)7077888;             // 4*768*768
  unsigned short* wall_ff1 = wall + (size_t)9437184;             // 4*3072*768
  unsigned short* wall_ff2 = wall + (size_t)18874368;            // 4*768*3072
  float* clsbuf = (float*)(wall + (size_t)28311552);
  float* sc_ws = clsbuf;                                         // 8192 floats
  float* partial = clsbuf + 8192;                                // 49152 floats
  float* cbuf_ws = partial + 49152;                              // 6144 floats
  float* c1_ws = cbuf_ws + 6144;                                 // 6144 floats
  float* pe_ws = c1_ws + 6144;                                   // 786432 floats
  float* allw = outp + 16;

  hipMemsetAsync(d_out, 0, (size_t)out_size * sizeof(float), stream);

  // PE table + upfront weight conversion (all layers)
  pe_init<<<3072, 256, 0, stream>>>(pe_ws);
  cvt_w_h<<<6912, 256, 0, stream>>>(in_w,  wall_in,  1769472);
  cvt_w_h<<<2304, 256, 0, stream>>>(out_w, wall_out,  589824);
  cvt_w_h<<<9216, 256, 0, stream>>>(ff_w1, wall_ff1, 2359296);
  cvt_w_h<<<9216, 256, 0, stream>>>(ff_w2, wall_ff2, 2359296);

  const int total4 = (int)(XN >> 2);
  embed_kernel<<<(total4 + 255) / 256, 256, 0, stream>>>(tokens, emb, pe_ws, x, total4);

  for (int l = 0; l < 4; ++l) {
    ln_kernel<<<2048, 256, 0, stream>>>(x, ln1_s + l * 768, ln1_b + l * 768, h_f16);
    gemm128<0><<<1152, 256, 0, stream>>>(h_f16, wall_in + (size_t)l * 1769472,
                                         in_b + l * 2304, bigu, 2304, 768, 18);
    attn_kernel<<<dim3(8, S_LEN / QT), 512, 0, stream>>>(bigu, mask, h_f16,
                                                         allw + (size_t)l * 8 * 1024 * 1024);
    gemm128<2><<<384, 256, 0, stream>>>(h_f16, wall_out + (size_t)l * 589824,
                                        out_b + l * 768, x, 768, 768, 6);
    ln_kernel<<<2048, 256, 0, stream>>>(x, ln2_s + l * 768, ln2_b + l * 768, h_f16);
    gemm128<1><<<1536, 256, 0, stream>>>(h_f16, wall_ff1 + (size_t)l * 2359296,
                                         ff_b1 + l * 3072, bigu, 3072, 768, 24);
    gemm128<2><<<384, 256, 0, stream>>>(bigu, wall_ff2 + (size_t)l * 2359296,
                                        ff_b2 + l * 768, x, 768, 3072, 6);
  }

  pool_score<<<2048, 256, 0, stream>>>(x, mask, pool_w, pool_b, sc_ws);
  pool_softmax<<<8, 256, 0, stream>>>(sc_ws);
  pool_sum<<<dim3(24, 8), 256, 0, stream>>>(x, sc_ws, partial);
  cls_ln<<<8, 256, 0, stream>>>(partial, cls_ln_s, cls_ln_b, cbuf_ws);
  cls_mlp1<<<dim3(192, 8), 256, 0, stream>>>(cbuf_ws, cls_w1, cls_b1, c1_ws);
  cls_logits<<<8, 256, 0, stream>>>(c1_ws, cls_w2, cls_b2, outp);
}

// Round 23
// 1276.281 us; speedup vs baseline: 1.0742x; 1.0416x over previous
//
#include <hip/hip_runtime.h>
#include <math.h>

#define S_LEN 1024
#define D_MODEL 768
#define NHEAD 12
#define NEG_INF -3.4028234663852886e38f

#define QT 32           // queries per attention block
#define KB 288          // key band per block = QT + 2*128

typedef _Float16 f16x8 __attribute__((ext_vector_type(8)));
typedef __attribute__((ext_vector_type(4))) float f32x4;

typedef const __attribute__((address_space(1))) unsigned int ga_u32;
typedef __attribute__((address_space(3))) unsigned int ls_u32;
__device__ __forceinline__ void gload16(const void* g, void* l) {
  __builtin_amdgcn_global_load_lds((ga_u32*)g, (ls_u32*)l, 16, 0, 0);
}

__device__ __forceinline__ float gelu_exact(float v) {
  return 0.5f * v * (1.0f + erff(v * 0.7071067811865475f));
}
__device__ __forceinline__ unsigned short f2h(float f) {
  union { _Float16 h; unsigned short u; } x; x.h = (_Float16)f; return x.u;
}
__device__ __forceinline__ float h2f(unsigned short u) {
  union { unsigned short u; _Float16 h; } x; x.u = u; return (float)x.h;
}

// ---------------- PE table init: pe[s][d], 1024x768 ----------------
__global__ __launch_bounds__(256) void pe_init(float* __restrict__ pe) {
  int i = blockIdx.x * 256 + threadIdx.x;
  if (i >= S_LEN * D_MODEL) return;
  int d = i % D_MODEL;
  int s = i / D_MODEL;
  float div = expf((float)(d & ~1) * (-9.210340371976184f / 768.0f));
  float ang = (float)s * div;
  pe[i] = (d & 1) ? cosf(ang) : sinf(ang);
}

// ---------------- embedding + PE table add -> fp16 residual ----------------
__global__ __launch_bounds__(256) void embed_kernel(
    const int* __restrict__ tok, const float* __restrict__ emb,
    const float* __restrict__ pe, unsigned short* __restrict__ X, int total4) {
  int i = blockIdx.x * 256 + threadIdx.x;
  if (i >= total4) return;
  int d4 = i % 192;
  int bs = i / 192;
  int s = bs & (S_LEN - 1);
  int t = tok[bs];
  float4 e = ((const float4*)emb)[(size_t)t * 192 + d4];
  float4 p = ((const float4*)pe)[(size_t)s * 192 + d4];
  ushort4 o;
  o.x = f2h(e.x + p.x); o.y = f2h(e.y + p.y);
  o.z = f2h(e.z + p.z); o.w = f2h(e.w + p.w);
  ((ushort4*)X)[i] = o;
}

// ---------------- weight convert: fp32 -> fp16 ----------------
__global__ __launch_bounds__(256) void cvt_w_h(
    const float* __restrict__ W, unsigned short* __restrict__ H, int n4) {
  int i = blockIdx.x * 256 + threadIdx.x;
  if (i >= n4) return;
  float4 w = ((const float4*)W)[i];
  ushort4 h;
  h.x = f2h(w.x); h.y = f2h(w.y); h.z = f2h(w.z); h.w = f2h(w.w);
  ((ushort4*)H)[i] = h;
}

// ---------------- LayerNorm (fp16 in): one wave per row, no LDS/barriers -------
__global__ __launch_bounds__(256) void ln_kernel(
    const unsigned short* __restrict__ X, const float* __restrict__ gam,
    const float* __restrict__ bet, unsigned short* __restrict__ Y) {
  const int tid = threadIdx.x;
  const int wave = tid >> 6, lane = tid & 63;
  const int row = blockIdx.x * 4 + wave;
  const unsigned short* xr = X + (size_t)row * D_MODEL;
  float v[12];
  float s = 0.0f;
#pragma unroll
  for (int c = 0; c < 3; ++c) {
    ushort4 u = *(const ushort4*)(xr + (lane << 2) + (c << 8));
    v[c * 4 + 0] = h2f(u.x); v[c * 4 + 1] = h2f(u.y);
    v[c * 4 + 2] = h2f(u.z); v[c * 4 + 3] = h2f(u.w);
    s += v[c * 4] + v[c * 4 + 1] + v[c * 4 + 2] + v[c * 4 + 3];
  }
#pragma unroll
  for (int o = 32; o; o >>= 1) s += __shfl_xor(s, o, 64);
  const float mean = s * (1.0f / 768.0f);
  float ss = 0.0f;
#pragma unroll
  for (int k = 0; k < 12; ++k) { float dd = v[k] - mean; ss += dd * dd; }
#pragma unroll
  for (int o = 32; o; o >>= 1) ss += __shfl_xor(ss, o, 64);
  const float rstd = rsqrtf(ss * (1.0f / 768.0f) + 1e-5f);
  unsigned short* yr = Y + (size_t)row * D_MODEL;
#pragma unroll
  for (int c = 0; c < 3; ++c) {
    const int d = (lane << 2) + (c << 8);
    float4 g = *(const float4*)(gam + d);
    float4 bb = *(const float4*)(bet + d);
    ushort4 o4;
    o4.x = f2h((v[c * 4 + 0] - mean) * rstd * g.x + bb.x);
    o4.y = f2h((v[c * 4 + 1] - mean) * rstd * g.y + bb.y);
    o4.z = f2h((v[c * 4 + 2] - mean) * rstd * g.z + bb.z);
    o4.w = f2h((v[c * 4 + 3] - mean) * rstd * g.w + bb.w);
    *(ushort4*)(yr + d) = o4;
  }
}

// ---------------- gemm128: 128x128 tile, BK=32, 4 waves, single-barrier 3-buffer --
// XCD chunk + 8x2 super-tile remap keeps per-XCD L2 working set ~2 MB.
// EPI 0: C_f16 = acc+bias   1: gelu   2: C_f16 += acc+bias (fp16 residual RMW)
template <int EPI>
__global__ __launch_bounds__(256) void gemm128(
    const unsigned short* __restrict__ A, const unsigned short* __restrict__ W,
    const float* __restrict__ bias, void* __restrict__ Cv,
    int N, int K, int NX) {
  __shared__ __align__(16) unsigned short SH[24576];  // 3 buffers x (A 8KB + B 8KB)
  const int tid = threadIdx.x;
  const int nwg = gridDim.x;
  const int wg = ((blockIdx.x & 7) * (nwg >> 3)) + (blockIdx.x >> 3);
  const int SX = NX >> 1;
  const int st = wg >> 4, w16 = wg & 15;
  const int ty = (st / SX) * 8 + (w16 >> 1);
  const int tx = (st % SX) * 2 + (w16 & 1);
  const int m0 = ty << 7, n0 = tx << 7;
  const int wave = tid >> 6, lane = tid & 63;
  const int wr = (wave >> 1) << 6, wc = (wave & 1) << 6;
  const int lq = lane >> 4, lr = lane & 15;
  const int rA0 = (wave << 5) + (lane >> 2);
  const int rA1 = rA0 + 16;
  const int sl = lane & 3;
  const size_t gA0 = (size_t)(m0 + rA0) * K + ((sl ^ ((rA0 >> 1) & 3)) << 3);
  const size_t gA1 = (size_t)(m0 + rA1) * K + ((sl ^ ((rA1 >> 1) & 3)) << 3);
  const size_t gB0 = (size_t)(n0 + rA0) * K + ((sl ^ ((rA0 >> 1) & 3)) << 3);
  const size_t gB1 = (size_t)(n0 + rA1) * K + ((sl ^ ((rA1 >> 1) & 3)) << 3);
  const int lws = wave << 10;

  const int nt = K >> 5;
  auto stage = [&](int buf, int t) {
    unsigned short* base = SH + (buf << 13);
    const int kk = t << 5;
    gload16(A + gA0 + kk, base + lws);
    gload16(A + gA1 + kk, base + lws + 512);
    gload16(W + gB0 + kk, base + 4096 + lws);
    gload16(W + gB1 + kk, base + 4096 + lws + 512);
  };
  stage(0, 0);
  stage(1, 1);

  f32x4 acc[4][4] = {};
  int cb = 0;                         // compute-buffer index (cycles 0,1,2)
  for (int t = 0; t < nt; ++t) {
    if (t + 1 < nt) {
      asm volatile("s_waitcnt vmcnt(4)" ::: "memory");   // tile t's 4 loads done
    } else {
      asm volatile("s_waitcnt vmcnt(0)" ::: "memory");
    }
    __builtin_amdgcn_s_barrier();                         // everyone's tile t ready
    __builtin_amdgcn_sched_barrier(0);
    const unsigned short* As = SH + (cb << 13);
    const unsigned short* Bs = As + 4096;
    f16x8 af[4], bq[4];
#pragma unroll
    for (int i = 0; i < 4; ++i) {
      int r = wr + (i << 4) + lr;
      af[i] = *(const f16x8*)&As[r * 32 + ((lq ^ ((r >> 1) & 3)) << 3)];
    }
#pragma unroll
    for (int j = 0; j < 4; ++j) {
      int r = wc + (j << 4) + lr;
      bq[j] = *(const f16x8*)&Bs[r * 32 + ((lq ^ ((r >> 1) & 3)) << 3)];
    }
    if (t + 2 < nt) {                 // stage overlaps the MFMA cluster
      int sb = cb + 2; if (sb >= 3) sb -= 3;
      stage(sb, t + 2);
    }
    __builtin_amdgcn_sched_barrier(0);                    // pin stage before MFMAs
    __builtin_amdgcn_s_setprio(1);
#pragma unroll
    for (int i = 0; i < 4; ++i)
#pragma unroll
      for (int j = 0; j < 4; ++j)
        acc[i][j] = __builtin_amdgcn_mfma_f32_16x16x32_f16(af[i], bq[j], acc[i][j], 0, 0, 0);
    __builtin_amdgcn_s_setprio(0);
    cb = (cb == 2) ? 0 : cb + 1;
  }
  // bias per j-fragment column
  float bval[4];
#pragma unroll
  for (int j = 0; j < 4; ++j) bval[j] = bias[n0 + wc + (j << 4) + lr];

  if (EPI == 2) {
    // fp16 residual RMW epilogue
    unsigned short* C = (unsigned short*)Cv;
#pragma unroll
    for (int j = 0; j < 4; ++j) {
      const int gcol = n0 + wc + (j << 4) + lr;
#pragma unroll
      for (int i = 0; i < 4; ++i) {
        const int grow0 = m0 + wr + (i << 4) + (lq << 2);
#pragma unroll
        for (int r = 0; r < 4; ++r) {
          size_t off = (size_t)(grow0 + r) * N + gcol;
          C[off] = f2h(h2f(C[off]) + acc[i][j][r] + bval[j]);
        }
      }
    }
    return;
  }

  unsigned short* C = (unsigned short*)Cv;
  __syncthreads();
  // repacked epilogue: two 64-row halves through LDS buffer 0, 16B/lane stores
#pragma unroll
  for (int hh = 0; hh < 2; ++hh) {
    if ((wave >> 1) == hh) {
#pragma unroll
      for (int i = 0; i < 4; ++i)
#pragma unroll
        for (int j = 0; j < 4; ++j) {
          const int colb = wc + (j << 4) + lr;
#pragma unroll
          for (int r = 0; r < 4; ++r) {
            const int rowl = (i << 4) + (lq << 2) + r;
            float v = acc[i][j][r] + bval[j];
            if (EPI == 1) v = gelu_exact(v);
            const int ch = (colb >> 3) ^ (rowl & 7);
            SH[rowl * 128 + (ch << 3) + (colb & 7)] = f2h(v);
          }
        }
    }
    __syncthreads();
#pragma unroll
    for (int it = 0; it < 4; ++it) {
      const int cid = tid + (it << 8);
      const int row = cid >> 4, ch = cid & 15;
      uint4 v8 = *(uint4*)&SH[row * 128 + ((ch ^ (row & 7)) << 3)];
      *(uint4*)&C[(size_t)(m0 + (hh << 6) + row) * N + n0 + (ch << 3)] = v8;
    }
    __syncthreads();
  }
}

// ---------------- banded attention: MFMA QK^T + softmax + MFMA PV (fp16) ---------
// grid (b, qtile): XCD = b. Vt slot swizzle = (d>>3)&7 (bijective in d-octet ->
// scatter writes spread across all 8 bank groups; reads stay 2-way/free).
__global__ __launch_bounds__(512) void attn_kernel(
    const unsigned short* __restrict__ qkv, const int* __restrict__ mask,
    unsigned short* __restrict__ attn_out, float* __restrict__ allw) {
  __shared__ __align__(16) unsigned short Ks[KB * 72];
  __shared__ __align__(16) unsigned short Vt[64 * 328];
  __shared__ __align__(16) unsigned short Qs[32 * 72];
  __shared__ __align__(16) unsigned short Ps[32 * 328];
  __shared__ __align__(16) float redmax[2][16][4];
  __shared__ __align__(16) float redsum[2][16][4];
  __shared__ int kvalid[KB];

  const int qt0 = blockIdx.y * QT;
  const int b = blockIdx.x;
  const int tid = threadIdx.x;
  const int w = tid >> 6, lane = tid & 63;
  const int lr = lane & 15, lg = lane >> 4;
  const int k0 = qt0 - 128;
  const int qh = w & 1, wq = w >> 1;
  const int nkt = (wq < 2) ? 5 : 4;

  for (int j = tid; j < KB; j += 512) {
    int key = k0 + j;
    kvalid[j] = (key >= 0 && key < S_LEN && mask[b * S_LEN + key] != 0) ? 1 : 0;
  }

  f32x4 pm[5] = {};
  const size_t rowbase = (size_t)(b * S_LEN) * 2304;
  const int qloc = lg << 2;
  const int qbase = (qh << 4) + qloc;

  for (int h = 0; h < NHEAD; ++h) {
    const int hoff = h << 6;
    if (tid < 256) {
      int r = tid >> 3, c = tid & 7;
      uint4 v = *(const uint4*)(qkv + rowbase + (size_t)(qt0 + r) * 2304 + hoff + (c << 3));
      *(uint4*)&Qs[r * 72 + ((c ^ (r & 7)) << 3)] = v;
    }
    for (int idx = tid; idx < 2304; idx += 512) {
      int r = idx >> 3, c = idx & 7;
      int key = k0 + r;
      uint4 kv = {0, 0, 0, 0}, vv = {0, 0, 0, 0};
      if ((unsigned)key < (unsigned)S_LEN) {
        const unsigned short* base = qkv + rowbase + (size_t)key * 2304 + hoff + (c << 3);
        kv = *(const uint4*)(base + 768);
        vv = *(const uint4*)(base + 1536);
      }
      *(uint4*)&Ks[r * 72 + ((c ^ (r & 7)) << 3)] = kv;
      const unsigned short* ve = (const unsigned short*)&vv;
      int jc = r >> 3, jw = r & 7;
#pragma unroll
      for (int e = 0; e < 8; ++e) {
        int d = (c << 3) + e;
        Vt[d * 328 + ((jc ^ ((d >> 3) & 7)) << 3) + jw] = ve[e];
      }
    }
    __syncthreads();

    f16x8 aq[2];
#pragma unroll
    for (int kc = 0; kc < 2; ++kc) {
      int r = (qh << 4) + lr;
      aq[kc] = *(f16x8*)&Qs[r * 72 + ((((kc << 2) + lg) ^ (r & 7)) << 3)];
    }
    f32x4 sc[5];
    __builtin_amdgcn_s_setprio(1);
#pragma unroll
    for (int t = 0; t < 5; ++t) {
      sc[t] = (f32x4){0.0f, 0.0f, 0.0f, 0.0f};
      if (t < nkt) {
        int r = ((wq + (t << 2)) << 4) + lr;
#pragma unroll
        for (int kc = 0; kc < 2; ++kc) {
          f16x8 bk = *(f16x8*)&Ks[r * 72 + ((((kc << 2) + lg) ^ (r & 7)) << 3)];
          sc[t] = __builtin_amdgcn_mfma_f32_16x16x32_f16(aq[kc], bk, sc[t], 0, 0, 0);
        }
      }
    }
    __builtin_amdgcn_s_setprio(0);
#pragma unroll
    for (int t = 0; t < 5; ++t) if (t < nkt) {
      int j = ((wq + (t << 2)) << 4) + lr;
      int okk = kvalid[j];
#pragma unroll
      for (int rg = 0; rg < 4; ++rg) {
        int q = qbase + rg;
        float s = sc[t][rg] * 0.125f;
        sc[t][rg] = (okk && j >= q && j <= q + 256) ? s : NEG_INF;
      }
    }
    float mx[4], zs[4];
#pragma unroll
    for (int rg = 0; rg < 4; ++rg) {
      float m = NEG_INF;
#pragma unroll
      for (int t = 0; t < 5; ++t) if (t < nkt) m = fmaxf(m, sc[t][rg]);
      mx[rg] = m;
    }
#pragma unroll
    for (int o = 1; o < 16; o <<= 1)
#pragma unroll
      for (int rg = 0; rg < 4; ++rg) mx[rg] = fmaxf(mx[rg], __shfl_xor(mx[rg], o, 64));
    if (lr == 0)
#pragma unroll
      for (int rg = 0; rg < 4; ++rg) redmax[qh][qloc + rg][wq] = mx[rg];
    __syncthreads();
#pragma unroll
    for (int rg = 0; rg < 4; ++rg) {
      f32x4 v = *(f32x4*)&redmax[qh][qloc + rg][0];
      mx[rg] = fmaxf(fmaxf(v[0], v[1]), fmaxf(v[2], v[3]));
      zs[rg] = 0.0f;
    }
#pragma unroll
    for (int t = 0; t < 5; ++t) if (t < nkt)
#pragma unroll
      for (int rg = 0; rg < 4; ++rg) {
        float e = expf(sc[t][rg] - mx[rg]);
        sc[t][rg] = e;
        zs[rg] += e;
      }
#pragma unroll
    for (int o = 1; o < 16; o <<= 1)
#pragma unroll
      for (int rg = 0; rg < 4; ++rg) zs[rg] += __shfl_xor(zs[rg], o, 64);
    if (lr == 0)
#pragma unroll
      for (int rg = 0; rg < 4; ++rg) redsum[qh][qloc + rg][wq] = zs[rg];
    __syncthreads();
#pragma unroll
    for (int rg = 0; rg < 4; ++rg) {
      f32x4 v = *(f32x4*)&redsum[qh][qloc + rg][0];
      zs[rg] = 1.0f / (v[0] + v[1] + v[2] + v[3]);
    }
#pragma unroll
    for (int t = 0; t < 5; ++t) if (t < nkt) {
      int j = ((wq + (t << 2)) << 4) + lr;
      int pc = j >> 3, pw = j & 7;
#pragma unroll
      for (int rg = 0; rg < 4; ++rg) {
        float p = sc[t][rg] * zs[rg];
        pm[t][rg] += p;
        int row = qbase + rg;
        Ps[row * 328 + ((pc ^ (row & 7)) << 3) + pw] = f2h(p);
      }
    }
    __syncthreads();
    {
      const int qt = w >> 2, dt = w & 3;
      const int ra = (qt << 4) + lr;
      const int rd = (dt << 4) + lr;
      f32x4 o4 = {0.0f, 0.0f, 0.0f, 0.0f};
      __builtin_amdgcn_s_setprio(1);
#pragma unroll
      for (int ks = 0; ks < 9; ++ks) {
        f16x8 pa = *(f16x8*)&Ps[ra * 328 + ((((ks << 2) + lg) ^ (ra & 7)) << 3)];
        f16x8 vb = *(f16x8*)&Vt[rd * 328 + ((((ks << 2) + lg) ^ ((rd >> 3) & 7)) << 3)];
        o4 = __builtin_amdgcn_mfma_f32_16x16x32_f16(pa, vb, o4, 0, 0, 0);
      }
      __builtin_amdgcn_s_setprio(0);
      unsigned short* op = attn_out +
          ((size_t)(b * S_LEN + qt0 + (qt << 4) + (lg << 2))) * D_MODEL + hoff + (dt << 4) + lr;
#pragma unroll
      for (int rg = 0; rg < 4; ++rg) op[(size_t)rg * D_MODEL] = f2h(o4[rg]);
    }
    __syncthreads();
  }

#pragma unroll
  for (int t = 0; t < 5; ++t) if (t < nkt) {
    int j = ((wq + (t << 2)) << 4) + lr;
    int key = k0 + j;
    if ((unsigned)key < (unsigned)S_LEN) {
      float* ap = allw + ((size_t)(b * S_LEN) + qt0 + qbase) * S_LEN + key;
#pragma unroll
      for (int rg = 0; rg < 4; ++rg) ap[(size_t)rg * S_LEN] = pm[t][rg] * (1.0f / 12.0f);
    }
  }
}

// ---------------- pooling stage 1: scores sc[b,s] = x·pool_w + pool_b ----------
__global__ __launch_bounds__(256) void pool_score(
    const unsigned short* __restrict__ X, const int* __restrict__ mask,
    const float* __restrict__ pool_w, const float* __restrict__ pool_b,
    float* __restrict__ sc) {
  const int tid = threadIdx.x;
  const int wave = tid >> 6, lane = tid & 63;
  const int row = blockIdx.x * 4 + wave;
  const unsigned short* xr = X + (size_t)row * D_MODEL;
  float acc = 0.0f;
#pragma unroll
  for (int c = 0; c < 3; ++c) {
    int d = (lane << 2) + (c << 8);
    ushort4 xv = *(const ushort4*)(xr + d);
    float4 wv = *(const float4*)(pool_w + d);
    acc += h2f(xv.x) * wv.x + h2f(xv.y) * wv.y + h2f(xv.z) * wv.z + h2f(xv.w) * wv.w;
  }
#pragma unroll
  for (int o = 32; o; o >>= 1) acc += __shfl_xor(acc, o, 64);
  if (lane == 0)
    sc[row] = (mask[row] == 0) ? NEG_INF : (acc + pool_b[0]);
}

// ---------------- pooling stage 2: softmax over S per batch (in-place) ---------
__global__ __launch_bounds__(256) void pool_softmax(float* __restrict__ sc) {
  __shared__ float scratch[4];
  __shared__ float buf[S_LEN];
  const int b = blockIdx.x;
  const int tid = threadIdx.x;
  float* sb = sc + b * S_LEN;
  float m = NEG_INF;
  for (int s = tid; s < S_LEN; s += 256) { buf[s] = sb[s]; m = fmaxf(m, buf[s]); }
#pragma unroll
  for (int o = 32; o; o >>= 1) m = fmaxf(m, __shfl_xor(m, o, 64));
  if ((tid & 63) == 0) scratch[tid >> 6] = m;
  __syncthreads();
  m = fmaxf(fmaxf(scratch[0], scratch[1]), fmaxf(scratch[2], scratch[3]));
  __syncthreads();
  float z = 0.0f;
  for (int s = tid; s < S_LEN; s += 256) { float e = expf(buf[s] - m); buf[s] = e; z += e; }
#pragma unroll
  for (int o = 32; o; o >>= 1) z += __shfl_xor(z, o, 64);
  if ((tid & 63) == 0) scratch[tid >> 6] = z;
  __syncthreads();
  float Z = scratch[0] + scratch[1] + scratch[2] + scratch[3];
  const float inv = 1.0f / Z;
  for (int s = tid; s < S_LEN; s += 256) sb[s] = buf[s] * inv;
}

// ---------------- pooling stage 3: partial weighted sums over s-chunks ---------
__global__ __launch_bounds__(256) void pool_sum(
    const unsigned short* __restrict__ X, const float* __restrict__ wgt,
    float* __restrict__ partial) {
  const int bx = blockIdx.x;            // dchunk*8 + schunk
  const int b = blockIdx.y;
  const int dchunk = bx >> 3, schunk = bx & 7;
  const int d = (dchunk << 8) + threadIdx.x;
  const int s0 = schunk << 7;
  const unsigned short* xb = X + ((size_t)(b << 10) + s0) * D_MODEL + d;
  const float* wb = wgt + (b << 10) + s0;
  float acc = 0.0f;
  for (int s = 0; s < 128; ++s) acc += wb[s] * h2f(xb[(size_t)s * D_MODEL]);
  partial[((size_t)((b << 3) + schunk)) * D_MODEL + d] = acc;
}

// ---------------- classifier stage A: reduce partials, tanh, LN -> cbuf --------
__global__ __launch_bounds__(256) void cls_ln(
    const float* __restrict__ partial,
    const float* __restrict__ ln_s, const float* __restrict__ ln_b,
    float* __restrict__ cbuf_g) {
  const int b = blockIdx.x;
  const int tid = threadIdx.x;
  __shared__ float scratch[4];
  __shared__ __align__(16) float pbuf[D_MODEL];
  for (int d = tid; d < D_MODEL; d += 256) {
    float acc = 0.0f;
#pragma unroll
    for (int p = 0; p < 8; ++p) acc += partial[((size_t)((b << 3) + p)) * D_MODEL + d];
    pbuf[d] = tanhf(acc);
  }
  __syncthreads();
  float ls = 0.0f;
  for (int d = tid; d < D_MODEL; d += 256) ls += pbuf[d];
#pragma unroll
  for (int o = 32; o; o >>= 1) ls += __shfl_xor(ls, o, 64);
  if ((tid & 63) == 0) scratch[tid >> 6] = ls;
  __syncthreads();
  float mean = (scratch[0] + scratch[1] + scratch[2] + scratch[3]) * (1.0f / 768.0f);
  __syncthreads();
  float vs = 0.0f;
  for (int d = tid; d < D_MODEL; d += 256) { float dd = pbuf[d] - mean; vs += dd * dd; }
#pragma unroll
  for (int o = 32; o; o >>= 1) vs += __shfl_xor(vs, o, 64);
  if ((tid & 63) == 0) scratch[tid >> 6] = vs;
  __syncthreads();
  float var = (scratch[0] + scratch[1] + scratch[2] + scratch[3]) * (1.0f / 768.0f);
  float rstd = rsqrtf(var + 1e-5f);
  for (int d = tid; d < D_MODEL; d += 256)
    cbuf_g[b * D_MODEL + d] = (pbuf[d] - mean) * rstd * ln_s[d] + ln_b[d];
}

// ---------------- classifier stage B: c1[b,i] = tanh(cbuf·w1[i] + b1[i]) --------
__global__ __launch_bounds__(256) void cls_mlp1(
    const float* __restrict__ cbuf_g, const float* __restrict__ w1,
    const float* __restrict__ b1, float* __restrict__ c1_g) {
  const int tid = threadIdx.x;
  const int wave = tid >> 6, lane = tid & 63;
  const int i = blockIdx.x * 4 + wave;
  const int b = blockIdx.y;
  __shared__ __align__(16) float cb[D_MODEL];
  for (int d = tid; d < D_MODEL; d += 256) cb[d] = cbuf_g[b * D_MODEL + d];
  __syncthreads();
  const float* wr = w1 + (size_t)i * D_MODEL;
  float acc = 0.0f;
#pragma unroll
  for (int c = 0; c < 3; ++c) {
    int d = (lane << 2) + (c << 8);
    float4 wv = *(const float4*)(wr + d);
    float4 cv = *(const float4*)(&cb[d]);
    acc += wv.x * cv.x + wv.y * cv.y + wv.z * cv.z + wv.w * cv.w;
  }
#pragma unroll
  for (int o = 32; o; o >>= 1) acc += __shfl_xor(acc, o, 64);
  if (lane == 0) c1_g[b * D_MODEL + i] = tanhf(acc + b1[i]);
}

// ---------------- classifier stage C: logits ----------------
__global__ __launch_bounds__(256) void cls_logits(
    const float* __restrict__ c1_g, const float* __restrict__ w2,
    const float* __restrict__ b2, float* __restrict__ out) {
  const int b = blockIdx.x;
  const int tid = threadIdx.x;
  __shared__ float scratch[4];
#pragma unroll
  for (int jc = 0; jc < 2; ++jc) {
    float acc = 0.0f;
    for (int i = tid; i < D_MODEL; i += 256) acc += c1_g[b * D_MODEL + i] * w2[jc * D_MODEL + i];
#pragma unroll
    for (int o = 32; o; o >>= 1) acc += __shfl_xor(acc, o, 64);
    if ((tid & 63) == 0) scratch[tid >> 6] = acc;
    __syncthreads();
    if (tid == 0) out[b * 2 + jc] = scratch[0] + scratch[1] + scratch[2] + scratch[3] + b2[jc];
    __syncthreads();
  }
}

extern "C" void kernel_launch(void* const* d_in, const int* in_sizes, int n_in,
                              void* d_out, int out_size, void* d_ws, size_t ws_size,
                              hipStream_t stream) {
  const int*   tokens  = (const int*)d_in[0];
  const int*   mask    = (const int*)d_in[1];
  const float* emb     = (const float*)d_in[2];
  const float* in_w    = (const float*)d_in[3];
  const float* in_b    = (const float*)d_in[4];
  const float* out_w   = (const float*)d_in[5];
  const float* out_b   = (const float*)d_in[6];
  const float* ln1_s   = (const float*)d_in[7];
  const float* ln1_b   = (const float*)d_in[8];
  const float* ln2_s   = (const float*)d_in[9];
  const float* ln2_b   = (const float*)d_in[10];
  const float* ff_w1   = (const float*)d_in[11];
  const float* ff_b1   = (const float*)d_in[12];
  const float* ff_w2   = (const float*)d_in[13];
  const float* ff_b2   = (const float*)d_in[14];
  const float* pool_w  = (const float*)d_in[15];
  const float* pool_b  = (const float*)d_in[16];
  const float* cls_ln_s = (const float*)d_in[17];
  const float* cls_ln_b = (const float*)d_in[18];
  const float* cls_w1  = (const float*)d_in[19];
  const float* cls_b1  = (const float*)d_in[20];
  const float* cls_w2  = (const float*)d_in[21];
  const float* cls_b2  = (const float*)d_in[22];

  float* outp = (float*)d_out;
  float* ws = (float*)d_ws;
  const size_t XN = (size_t)8 * 1024 * 768;          // 6,291,456
  const size_t BIGU = (size_t)8192 * 3072;           // 25,165,824 ushorts
  unsigned short* x = (unsigned short*)ws;                       // fp16 residual
  unsigned short* bigu = (unsigned short*)(ws + XN);             // fp16 qkv / gelu
  unsigned short* h_f16 = (unsigned short*)(ws + XN + BIGU / 2); // fp16 activations
  unsigned short* wall = h_f16 + XN;                             // fp16 weight arena
  unsigned short* wall_in  = wall;                               // 4*2304*768
  unsigned short* wall_out = wall + (size_t)7077888;             // 4*768*768
  unsigned short* wall_ff1 = wall + (size_t)9437184;             // 4*3072*768
  unsigned short* wall_ff2 = wall + (size_t)18874368;            // 4*768*3072
  float* clsbuf = (float*)(wall + (size_t)28311552);
  float* sc_ws = clsbuf;                                         // 8192 floats
  float* partial = clsbuf + 8192;                                // 49152 floats
  float* cbuf_ws = partial + 49152;                              // 6144 floats
  float* c1_ws = cbuf_ws + 6144;                                 // 6144 floats
  float* pe_ws = c1_ws + 6144;                                   // 786432 floats
  float* allw = outp + 16;

  hipMemsetAsync(d_out, 0, (size_t)out_size * sizeof(float), stream);

  // PE table + upfront weight conversion (all layers)
  pe_init<<<3072, 256, 0, stream>>>(pe_ws);
  cvt_w_h<<<6912, 256, 0, stream>>>(in_w,  wall_in,  1769472);
  cvt_w_h<<<2304, 256, 0, stream>>>(out_w, wall_out,  589824);
  cvt_w_h<<<9216, 256, 0, stream>>>(ff_w1, wall_ff1, 2359296);
  cvt_w_h<<<9216, 256, 0, stream>>>(ff_w2, wall_ff2, 2359296);

  const int total4 = (int)(XN >> 2);
  embed_kernel<<<(total4 + 255) / 256, 256, 0, stream>>>(tokens, emb, pe_ws, x, total4);

  for (int l = 0; l < 4; ++l) {
    ln_kernel<<<2048, 256, 0, stream>>>(x, ln1_s + l * 768, ln1_b + l * 768, h_f16);
    gemm128<0><<<1152, 256, 0, stream>>>(h_f16, wall_in + (size_t)l * 1769472,
                                         in_b + l * 2304, bigu, 2304, 768, 18);
    attn_kernel<<<dim3(8, S_LEN / QT), 512, 0, stream>>>(bigu, mask, h_f16,
                                                         allw + (size_t)l * 8 * 1024 * 1024);
    gemm128<2><<<384, 256, 0, stream>>>(h_f16, wall_out + (size_t)l * 589824,
                                        out_b + l * 768, x, 768, 768, 6);
    ln_kernel<<<2048, 256, 0, stream>>>(x, ln2_s + l * 768, ln2_b + l * 768, h_f16);
    gemm128<1><<<1536, 256, 0, stream>>>(h_f16, wall_ff1 + (size_t)l * 2359296,
                                         ff_b1 + l * 3072, bigu, 3072, 768, 24);
    gemm128<2><<<384, 256, 0, stream>>>(bigu, wall_ff2 + (size_t)l * 2359296,
                                        ff_b2 + l * 768, x, 768, 3072, 6);
  }

  pool_score<<<2048, 256, 0, stream>>>(x, mask, pool_w, pool_b, sc_ws);
  pool_softmax<<<8, 256, 0, stream>>>(sc_ws);
  pool_sum<<<dim3(24, 8), 256, 0, stream>>>(x, sc_ws, partial);
  cls_ln<<<8, 256, 0, stream>>>(partial, cls_ln_s, cls_ln_b, cbuf_ws);
  cls_mlp1<<<dim3(192, 8), 256, 0, stream>>>(cbuf_ws, cls_w1, cls_b1, c1_ws);
  cls_logits<<<8, 256, 0, stream>>>(c1_ws, cls_w2, cls_b2, outp);
}

// Round 24
// 1270.587 us; speedup vs baseline: 1.0790x; 1.0045x over previous
//
#include <hip/hip_runtime.h>
#include <math.h>

#define S_LEN 1024
#define D_MODEL 768
#define NHEAD 12
#define NEG_INF -3.4028234663852886e38f

#define QT 32           // queries per attention block
#define KB 288          // key band per block = QT + 2*128

typedef _Float16 f16x8 __attribute__((ext_vector_type(8)));
typedef __attribute__((ext_vector_type(4))) float f32x4;

typedef const __attribute__((address_space(1))) unsigned int ga_u32;
typedef __attribute__((address_space(3))) unsigned int ls_u32;
__device__ __forceinline__ void gload16(const void* g, void* l) {
  __builtin_amdgcn_global_load_lds((ga_u32*)g, (ls_u32*)l, 16, 0, 0);
}

__device__ __forceinline__ float gelu_exact(float v) {
  return 0.5f * v * (1.0f + erff(v * 0.7071067811865475f));
}
__device__ __forceinline__ unsigned short f2h(float f) {
  union { _Float16 h; unsigned short u; } x; x.h = (_Float16)f; return x.u;
}
__device__ __forceinline__ float h2f(unsigned short u) {
  union { unsigned short u; _Float16 h; } x; x.u = u; return (float)x.h;
}

// ---------------- PE table init: pe[s][d], 1024x768 ----------------
__global__ __launch_bounds__(256) void pe_init(float* __restrict__ pe) {
  int i = blockIdx.x * 256 + threadIdx.x;
  if (i >= S_LEN * D_MODEL) return;
  int d = i % D_MODEL;
  int s = i / D_MODEL;
  float div = expf((float)(d & ~1) * (-9.210340371976184f / 768.0f));
  float ang = (float)s * div;
  pe[i] = (d & 1) ? cosf(ang) : sinf(ang);
}

// ---------------- embedding + PE table add -> fp16 residual ----------------
__global__ __launch_bounds__(256) void embed_kernel(
    const int* __restrict__ tok, const float* __restrict__ emb,
    const float* __restrict__ pe, unsigned short* __restrict__ X, int total4) {
  int i = blockIdx.x * 256 + threadIdx.x;
  if (i >= total4) return;
  int d4 = i % 192;
  int bs = i / 192;
  int s = bs & (S_LEN - 1);
  int t = tok[bs];
  float4 e = ((const float4*)emb)[(size_t)t * 192 + d4];
  float4 p = ((const float4*)pe)[(size_t)s * 192 + d4];
  ushort4 o;
  o.x = f2h(e.x + p.x); o.y = f2h(e.y + p.y);
  o.z = f2h(e.z + p.z); o.w = f2h(e.w + p.w);
  ((ushort4*)X)[i] = o;
}

// ---------------- weight convert: fp32 -> fp16 ----------------
__global__ __launch_bounds__(256) void cvt_w_h(
    const float* __restrict__ W, unsigned short* __restrict__ H, int n4) {
  int i = blockIdx.x * 256 + threadIdx.x;
  if (i >= n4) return;
  float4 w = ((const float4*)W)[i];
  ushort4 h;
  h.x = f2h(w.x); h.y = f2h(w.y); h.z = f2h(w.z); h.w = f2h(w.w);
  ((ushort4*)H)[i] = h;
}

// ---------------- LayerNorm (fp16 in): one wave per row, no LDS/barriers -------
__global__ __launch_bounds__(256) void ln_kernel(
    const unsigned short* __restrict__ X, const float* __restrict__ gam,
    const float* __restrict__ bet, unsigned short* __restrict__ Y) {
  const int tid = threadIdx.x;
  const int wave = tid >> 6, lane = tid & 63;
  const int row = blockIdx.x * 4 + wave;
  const unsigned short* xr = X + (size_t)row * D_MODEL;
  float v[12];
  float s = 0.0f;
#pragma unroll
  for (int c = 0; c < 3; ++c) {
    ushort4 u = *(const ushort4*)(xr + (lane << 2) + (c << 8));
    v[c * 4 + 0] = h2f(u.x); v[c * 4 + 1] = h2f(u.y);
    v[c * 4 + 2] = h2f(u.z); v[c * 4 + 3] = h2f(u.w);
    s += v[c * 4] + v[c * 4 + 1] + v[c * 4 + 2] + v[c * 4 + 3];
  }
#pragma unroll
  for (int o = 32; o; o >>= 1) s += __shfl_xor(s, o, 64);
  const float mean = s * (1.0f / 768.0f);
  float ss = 0.0f;
#pragma unroll
  for (int k = 0; k < 12; ++k) { float dd = v[k] - mean; ss += dd * dd; }
#pragma unroll
  for (int o = 32; o; o >>= 1) ss += __shfl_xor(ss, o, 64);
  const float rstd = rsqrtf(ss * (1.0f / 768.0f) + 1e-5f);
  unsigned short* yr = Y + (size_t)row * D_MODEL;
#pragma unroll
  for (int c = 0; c < 3; ++c) {
    const int d = (lane << 2) + (c << 8);
    float4 g = *(const float4*)(gam + d);
    float4 bb = *(const float4*)(bet + d);
    ushort4 o4;
    o4.x = f2h((v[c * 4 + 0] - mean) * rstd * g.x + bb.x);
    o4.y = f2h((v[c * 4 + 1] - mean) * rstd * g.y + bb.y);
    o4.z = f2h((v[c * 4 + 2] - mean) * rstd * g.z + bb.z);
    o4.w = f2h((v[c * 4 + 3] - mean) * rstd * g.w + bb.w);
    *(ushort4*)(yr + d) = o4;
  }
}

// ---------------- gemm128: 128x128 tile, BK=32, 4 waves, single-barrier 3-buffer --
// XCD chunk + 8x2 super-tile remap keeps per-XCD L2 working set ~2 MB.
// EPI 0: C_f16 = acc+bias   1: gelu   2: C_f16 += acc+bias (fp16 residual RMW)
template <int EPI>
__global__ __launch_bounds__(256) void gemm128(
    const unsigned short* __restrict__ A, const unsigned short* __restrict__ W,
    const float* __restrict__ bias, void* __restrict__ Cv,
    int N, int K, int NX) {
  __shared__ __align__(16) unsigned short SH[24576];  // 3 buffers x (A 8KB + B 8KB)
  const int tid = threadIdx.x;
  const int nwg = gridDim.x;
  const int wg = ((blockIdx.x & 7) * (nwg >> 3)) + (blockIdx.x >> 3);
  const int SX = NX >> 1;
  const int st = wg >> 4, w16 = wg & 15;
  const int ty = (st / SX) * 8 + (w16 >> 1);
  const int tx = (st % SX) * 2 + (w16 & 1);
  const int m0 = ty << 7, n0 = tx << 7;
  const int wave = tid >> 6, lane = tid & 63;
  const int wr = (wave >> 1) << 6, wc = (wave & 1) << 6;
  const int lq = lane >> 4, lr = lane & 15;
  const int rA0 = (wave << 5) + (lane >> 2);
  const int rA1 = rA0 + 16;
  const int sl = lane & 3;
  const size_t gA0 = (size_t)(m0 + rA0) * K + ((sl ^ ((rA0 >> 1) & 3)) << 3);
  const size_t gA1 = (size_t)(m0 + rA1) * K + ((sl ^ ((rA1 >> 1) & 3)) << 3);
  const size_t gB0 = (size_t)(n0 + rA0) * K + ((sl ^ ((rA0 >> 1) & 3)) << 3);
  const size_t gB1 = (size_t)(n0 + rA1) * K + ((sl ^ ((rA1 >> 1) & 3)) << 3);
  const int lws = wave << 10;

  const int nt = K >> 5;
  auto stage = [&](int buf, int t) {
    unsigned short* base = SH + (buf << 13);
    const int kk = t << 5;
    gload16(A + gA0 + kk, base + lws);
    gload16(A + gA1 + kk, base + lws + 512);
    gload16(W + gB0 + kk, base + 4096 + lws);
    gload16(W + gB1 + kk, base + 4096 + lws + 512);
  };
  stage(0, 0);
  stage(1, 1);

  f32x4 acc[4][4] = {};
  int cb = 0;                         // compute-buffer index (cycles 0,1,2)
  for (int t = 0; t < nt; ++t) {
    if (t + 1 < nt) {
      asm volatile("s_waitcnt vmcnt(4)" ::: "memory");   // tile t's 4 loads done
    } else {
      asm volatile("s_waitcnt vmcnt(0)" ::: "memory");
    }
    __builtin_amdgcn_s_barrier();                         // everyone's tile t ready
    __builtin_amdgcn_sched_barrier(0);
    const unsigned short* As = SH + (cb << 13);
    const unsigned short* Bs = As + 4096;
    f16x8 af[4], bq[4];
#pragma unroll
    for (int i = 0; i < 4; ++i) {
      int r = wr + (i << 4) + lr;
      af[i] = *(const f16x8*)&As[r * 32 + ((lq ^ ((r >> 1) & 3)) << 3)];
    }
#pragma unroll
    for (int j = 0; j < 4; ++j) {
      int r = wc + (j << 4) + lr;
      bq[j] = *(const f16x8*)&Bs[r * 32 + ((lq ^ ((r >> 1) & 3)) << 3)];
    }
    if (t + 2 < nt) {                 // stage overlaps the MFMA cluster
      int sb = cb + 2; if (sb >= 3) sb -= 3;
      stage(sb, t + 2);
    }
    __builtin_amdgcn_sched_barrier(0);                    // pin stage before MFMAs
    __builtin_amdgcn_s_setprio(1);
#pragma unroll
    for (int i = 0; i < 4; ++i)
#pragma unroll
      for (int j = 0; j < 4; ++j)
        acc[i][j] = __builtin_amdgcn_mfma_f32_16x16x32_f16(af[i], bq[j], acc[i][j], 0, 0, 0);
    __builtin_amdgcn_s_setprio(0);
    cb = (cb == 2) ? 0 : cb + 1;
  }
  // bias per j-fragment column
  float bval[4];
#pragma unroll
  for (int j = 0; j < 4; ++j) bval[j] = bias[n0 + wc + (j << 4) + lr];

  if (EPI == 2) {
    // fp16 residual RMW epilogue
    unsigned short* C = (unsigned short*)Cv;
#pragma unroll
    for (int j = 0; j < 4; ++j) {
      const int gcol = n0 + wc + (j << 4) + lr;
#pragma unroll
      for (int i = 0; i < 4; ++i) {
        const int grow0 = m0 + wr + (i << 4) + (lq << 2);
#pragma unroll
        for (int r = 0; r < 4; ++r) {
          size_t off = (size_t)(grow0 + r) * N + gcol;
          C[off] = f2h(h2f(C[off]) + acc[i][j][r] + bval[j]);
        }
      }
    }
    return;
  }

  unsigned short* C = (unsigned short*)Cv;
  __syncthreads();
  // repacked epilogue: two 64-row halves through LDS buffer 0, 16B/lane stores
#pragma unroll
  for (int hh = 0; hh < 2; ++hh) {
    if ((wave >> 1) == hh) {
#pragma unroll
      for (int i = 0; i < 4; ++i)
#pragma unroll
        for (int j = 0; j < 4; ++j) {
          const int colb = wc + (j << 4) + lr;
#pragma unroll
          for (int r = 0; r < 4; ++r) {
            const int rowl = (i << 4) + (lq << 2) + r;
            float v = acc[i][j][r] + bval[j];
            if (EPI == 1) v = gelu_exact(v);
            const int ch = (colb >> 3) ^ (rowl & 7);
            SH[rowl * 128 + (ch << 3) + (colb & 7)] = f2h(v);
          }
        }
    }
    __syncthreads();
#pragma unroll
    for (int it = 0; it < 4; ++it) {
      const int cid = tid + (it << 8);
      const int row = cid >> 4, ch = cid & 15;
      uint4 v8 = *(uint4*)&SH[row * 128 + ((ch ^ (row & 7)) << 3)];
      *(uint4*)&C[(size_t)(m0 + (hh << 6) + row) * N + n0 + (ch << 3)] = v8;
    }
    __syncthreads();
  }
}

// ---------------- banded attention: MFMA QK^T + softmax + MFMA PV (fp16) ---------
// grid (b, qtile): XCD = b. K/Q staged via global_load_lds (linear LDS rows of
// 64 fp16, per-lane pre-swizzled global source). OOB K rows stay stale but are
// always masked to NEG_INF via kvalid before use. V reg-staged transposed
// (zero-filled OOB), slot swizzle (d>>3)&7.
__global__ __launch_bounds__(512) void attn_kernel(
    const unsigned short* __restrict__ qkv, const int* __restrict__ mask,
    unsigned short* __restrict__ attn_out, float* __restrict__ allw) {
  __shared__ __align__(16) unsigned short Ks[KB * 64];
  __shared__ __align__(16) unsigned short Vt[64 * 328];
  __shared__ __align__(16) unsigned short Qs[32 * 64];
  __shared__ __align__(16) unsigned short Ps[32 * 328];
  __shared__ __align__(16) float redmax[2][16][4];
  __shared__ __align__(16) float redsum[2][16][4];
  __shared__ int kvalid[KB];

  const int qt0 = blockIdx.y * QT;
  const int b = blockIdx.x;
  const int tid = threadIdx.x;
  const int w = tid >> 6, lane = tid & 63;
  const int lr = lane & 15, lg = lane >> 4;
  const int k0 = qt0 - 128;
  const int qh = w & 1, wq = w >> 1;
  const int nkt = (wq < 2) ? 5 : 4;

  for (int j = tid; j < KB; j += 512) {
    int key = k0 + j;
    kvalid[j] = (key >= 0 && key < S_LEN && mask[b * S_LEN + key] != 0) ? 1 : 0;
  }

  f32x4 pm[5] = {};
  const size_t rowbase = (size_t)(b * S_LEN) * 2304;
  const int qloc = lg << 2;
  const int qbase = (qh << 4) + qloc;
  const int sci = (w << 6) + lane;         // pass-0 chunk index for this thread
  const int sr = sci >> 3, sc8 = sci & 7;  // row / chunk-in-row

  for (int h = 0; h < NHEAD; ++h) {
    const int hoff = h << 6;
    // ---- Q via global_load_lds: 256 chunks, waves 0..3 (wave-uniform dest) ----
    if (w < 4) {
      unsigned short* qdst = Qs + ((size_t)(w << 6) << 3);
      gload16(qkv + rowbase + (size_t)(qt0 + sr) * 2304 + hoff + ((sc8 ^ (sr & 7)) << 3), qdst);
    }
    // ---- K via global_load_lds: 2304 chunks = 4.5 wave-passes ----
#pragma unroll
    for (int p = 0; p < 5; ++p) {
      const int cbase = (p << 9) + (w << 6);
      if (cbase < 2304) {
        const int ci = cbase + lane;
        const int r = ci >> 3, c = ci & 7;
        const int key = k0 + r;
        unsigned short* kdst = Ks + ((size_t)cbase << 3);
        if ((unsigned)key < (unsigned)S_LEN)
          gload16(qkv + rowbase + (size_t)key * 2304 + hoff + 768 + ((c ^ (r & 7)) << 3), kdst);
      }
    }
    // ---- V reg-staged transposed (zero-filled OOB) ----
    for (int idx = tid; idx < 2304; idx += 512) {
      int r = idx >> 3, c = idx & 7;
      int key = k0 + r;
      uint4 vv = {0, 0, 0, 0};
      if ((unsigned)key < (unsigned)S_LEN)
        vv = *(const uint4*)(qkv + rowbase + (size_t)key * 2304 + hoff + 1536 + (c << 3));
      const unsigned short* ve = (const unsigned short*)&vv;
      int jc = r >> 3, jw = r & 7;
#pragma unroll
      for (int e = 0; e < 8; ++e) {
        int d = (c << 3) + e;
        Vt[d * 328 + ((jc ^ ((d >> 3) & 7)) << 3) + jw] = ve[e];
      }
    }
    __syncthreads();

    f16x8 aq[2];
#pragma unroll
    for (int kc = 0; kc < 2; ++kc) {
      int r = (qh << 4) + lr;
      aq[kc] = *(f16x8*)&Qs[(r << 6) + ((((kc << 2) + lg) ^ (r & 7)) << 3)];
    }
    f32x4 sc[5];
    __builtin_amdgcn_s_setprio(1);
#pragma unroll
    for (int t = 0; t < 5; ++t) {
      sc[t] = (f32x4){0.0f, 0.0f, 0.0f, 0.0f};
      if (t < nkt) {
        int r = ((wq + (t << 2)) << 4) + lr;
#pragma unroll
        for (int kc = 0; kc < 2; ++kc) {
          f16x8 bk = *(f16x8*)&Ks[(r << 6) + ((((kc << 2) + lg) ^ (r & 7)) << 3)];
          sc[t] = __builtin_amdgcn_mfma_f32_16x16x32_f16(aq[kc], bk, sc[t], 0, 0, 0);
        }
      }
    }
    __builtin_amdgcn_s_setprio(0);
#pragma unroll
    for (int t = 0; t < 5; ++t) if (t < nkt) {
      int j = ((wq + (t << 2)) << 4) + lr;
      int okk = kvalid[j];
#pragma unroll
      for (int rg = 0; rg < 4; ++rg) {
        int q = qbase + rg;
        float s = sc[t][rg] * 0.125f;
        sc[t][rg] = (okk && j >= q && j <= q + 256) ? s : NEG_INF;
      }
    }
    float mx[4], zs[4];
#pragma unroll
    for (int rg = 0; rg < 4; ++rg) {
      float m = NEG_INF;
#pragma unroll
      for (int t = 0; t < 5; ++t) if (t < nkt) m = fmaxf(m, sc[t][rg]);
      mx[rg] = m;
    }
#pragma unroll
    for (int o = 1; o < 16; o <<= 1)
#pragma unroll
      for (int rg = 0; rg < 4; ++rg) mx[rg] = fmaxf(mx[rg], __shfl_xor(mx[rg], o, 64));
    if (lr == 0)
#pragma unroll
      for (int rg = 0; rg < 4; ++rg) redmax[qh][qloc + rg][wq] = mx[rg];
    __syncthreads();
#pragma unroll
    for (int rg = 0; rg < 4; ++rg) {
      f32x4 v = *(f32x4*)&redmax[qh][qloc + rg][0];
      mx[rg] = fmaxf(fmaxf(v[0], v[1]), fmaxf(v[2], v[3]));
      zs[rg] = 0.0f;
    }
#pragma unroll
    for (int t = 0; t < 5; ++t) if (t < nkt)
#pragma unroll
      for (int rg = 0; rg < 4; ++rg) {
        float e = expf(sc[t][rg] - mx[rg]);
        sc[t][rg] = e;
        zs[rg] += e;
      }
#pragma unroll
    for (int o = 1; o < 16; o <<= 1)
#pragma unroll
      for (int rg = 0; rg < 4; ++rg) zs[rg] += __shfl_xor(zs[rg], o, 64);
    if (lr == 0)
#pragma unroll
      for (int rg = 0; rg < 4; ++rg) redsum[qh][qloc + rg][wq] = zs[rg];
    __syncthreads();
#pragma unroll
    for (int rg = 0; rg < 4; ++rg) {
      f32x4 v = *(f32x4*)&redsum[qh][qloc + rg][0];
      zs[rg] = 1.0f / (v[0] + v[1] + v[2] + v[3]);
    }
#pragma unroll
    for (int t = 0; t < 5; ++t) if (t < nkt) {
      int j = ((wq + (t << 2)) << 4) + lr;
      int pc = j >> 3, pw = j & 7;
#pragma unroll
      for (int rg = 0; rg < 4; ++rg) {
        float p = sc[t][rg] * zs[rg];
        pm[t][rg] += p;
        int row = qbase + rg;
        Ps[row * 328 + ((pc ^ (row & 7)) << 3) + pw] = f2h(p);
      }
    }
    __syncthreads();
    {
      const int qt = w >> 2, dt = w & 3;
      const int ra = (qt << 4) + lr;
      const int rd = (dt << 4) + lr;
      f32x4 o4 = {0.0f, 0.0f, 0.0f, 0.0f};
      __builtin_amdgcn_s_setprio(1);
#pragma unroll
      for (int ks = 0; ks < 9; ++ks) {
        f16x8 pa = *(f16x8*)&Ps[ra * 328 + ((((ks << 2) + lg) ^ (ra & 7)) << 3)];
        f16x8 vb = *(f16x8*)&Vt[rd * 328 + ((((ks << 2) + lg) ^ ((rd >> 3) & 7)) << 3)];
        o4 = __builtin_amdgcn_mfma_f32_16x16x32_f16(pa, vb, o4, 0, 0, 0);
      }
      __builtin_amdgcn_s_setprio(0);
      unsigned short* op = attn_out +
          ((size_t)(b * S_LEN + qt0 + (qt << 4) + (lg << 2))) * D_MODEL + hoff + (dt << 4) + lr;
#pragma unroll
      for (int rg = 0; rg < 4; ++rg) op[(size_t)rg * D_MODEL] = f2h(o4[rg]);
    }
    __syncthreads();
  }

#pragma unroll
  for (int t = 0; t < 5; ++t) if (t < nkt) {
    int j = ((wq + (t << 2)) << 4) + lr;
    int key = k0 + j;
    if ((unsigned)key < (unsigned)S_LEN) {
      float* ap = allw + ((size_t)(b * S_LEN) + qt0 + qbase) * S_LEN + key;
#pragma unroll
      for (int rg = 0; rg < 4; ++rg) ap[(size_t)rg * S_LEN] = pm[t][rg] * (1.0f / 12.0f);
    }
  }
}

// ---------------- pooling stage 1: scores sc[b,s] = x·pool_w + pool_b ----------
__global__ __launch_bounds__(256) void pool_score(
    const unsigned short* __restrict__ X, const int* __restrict__ mask,
    const float* __restrict__ pool_w, const float* __restrict__ pool_b,
    float* __restrict__ sc) {
  const int tid = threadIdx.x;
  const int wave = tid >> 6, lane = tid & 63;
  const int row = blockIdx.x * 4 + wave;
  const unsigned short* xr = X + (size_t)row * D_MODEL;
  float acc = 0.0f;
#pragma unroll
  for (int c = 0; c < 3; ++c) {
    int d = (lane << 2) + (c << 8);
    ushort4 xv = *(const ushort4*)(xr + d);
    float4 wv = *(const float4*)(pool_w + d);
    acc += h2f(xv.x) * wv.x + h2f(xv.y) * wv.y + h2f(xv.z) * wv.z + h2f(xv.w) * wv.w;
  }
#pragma unroll
  for (int o = 32; o; o >>= 1) acc += __shfl_xor(acc, o, 64);
  if (lane == 0)
    sc[row] = (mask[row] == 0) ? NEG_INF : (acc + pool_b[0]);
}

// ---------------- pooling stage 2: softmax over S per batch (in-place) ---------
__global__ __launch_bounds__(256) void pool_softmax(float* __restrict__ sc) {
  __shared__ float scratch[4];
  __shared__ float buf[S_LEN];
  const int b = blockIdx.x;
  const int tid = threadIdx.x;
  float* sb = sc + b * S_LEN;
  float m = NEG_INF;
  for (int s = tid; s < S_LEN; s += 256) { buf[s] = sb[s]; m = fmaxf(m, buf[s]); }
#pragma unroll
  for (int o = 32; o; o >>= 1) m = fmaxf(m, __shfl_xor(m, o, 64));
  if ((tid & 63) == 0) scratch[tid >> 6] = m;
  __syncthreads();
  m = fmaxf(fmaxf(scratch[0], scratch[1]), fmaxf(scratch[2], scratch[3]));
  __syncthreads();
  float z = 0.0f;
  for (int s = tid; s < S_LEN; s += 256) { float e = expf(buf[s] - m); buf[s] = e; z += e; }
#pragma unroll
  for (int o = 32; o; o >>= 1) z += __shfl_xor(z, o, 64);
  if ((tid & 63) == 0) scratch[tid >> 6] = z;
  __syncthreads();
  float Z = scratch[0] + scratch[1] + scratch[2] + scratch[3];
  const float inv = 1.0f / Z;
  for (int s = tid; s < S_LEN; s += 256) sb[s] = buf[s] * inv;
}

// ---------------- pooling stage 3: partial weighted sums over s-chunks ---------
__global__ __launch_bounds__(256) void pool_sum(
    const unsigned short* __restrict__ X, const float* __restrict__ wgt,
    float* __restrict__ partial) {
  const int bx = blockIdx.x;            // dchunk*8 + schunk
  const int b = blockIdx.y;
  const int dchunk = bx >> 3, schunk = bx & 7;
  const int d = (dchunk << 8) + threadIdx.x;
  const int s0 = schunk << 7;
  const unsigned short* xb = X + ((size_t)(b << 10) + s0) * D_MODEL + d;
  const float* wb = wgt + (b << 10) + s0;
  float acc = 0.0f;
  for (int s = 0; s < 128; ++s) acc += wb[s] * h2f(xb[(size_t)s * D_MODEL]);
  partial[((size_t)((b << 3) + schunk)) * D_MODEL + d] = acc;
}

// ---------------- classifier stage A: reduce partials, tanh, LN -> cbuf --------
__global__ __launch_bounds__(256) void cls_ln(
    const float* __restrict__ partial,
    const float* __restrict__ ln_s, const float* __restrict__ ln_b,
    float* __restrict__ cbuf_g) {
  const int b = blockIdx.x;
  const int tid = threadIdx.x;
  __shared__ float scratch[4];
  __shared__ __align__(16) float pbuf[D_MODEL];
  for (int d = tid; d < D_MODEL; d += 256) {
    float acc = 0.0f;
#pragma unroll
    for (int p = 0; p < 8; ++p) acc += partial[((size_t)((b << 3) + p)) * D_MODEL + d];
    pbuf[d] = tanhf(acc);
  }
  __syncthreads();
  float ls = 0.0f;
  for (int d = tid; d < D_MODEL; d += 256) ls += pbuf[d];
#pragma unroll
  for (int o = 32; o; o >>= 1) ls += __shfl_xor(ls, o, 64);
  if ((tid & 63) == 0) scratch[tid >> 6] = ls;
  __syncthreads();
  float mean = (scratch[0] + scratch[1] + scratch[2] + scratch[3]) * (1.0f / 768.0f);
  __syncthreads();
  float vs = 0.0f;
  for (int d = tid; d < D_MODEL; d += 256) { float dd = pbuf[d] - mean; vs += dd * dd; }
#pragma unroll
  for (int o = 32; o; o >>= 1) vs += __shfl_xor(vs, o, 64);
  if ((tid & 63) == 0) scratch[tid >> 6] = vs;
  __syncthreads();
  float var = (scratch[0] + scratch[1] + scratch[2] + scratch[3]) * (1.0f / 768.0f);
  float rstd = rsqrtf(var + 1e-5f);
  for (int d = tid; d < D_MODEL; d += 256)
    cbuf_g[b * D_MODEL + d] = (pbuf[d] - mean) * rstd * ln_s[d] + ln_b[d];
}

// ---------------- classifier stage B: c1[b,i] = tanh(cbuf·w1[i] + b1[i]) --------
__global__ __launch_bounds__(256) void cls_mlp1(
    const float* __restrict__ cbuf_g, const float* __restrict__ w1,
    const float* __restrict__ b1, float* __restrict__ c1_g) {
  const int tid = threadIdx.x;
  const int wave = tid >> 6, lane = tid & 63;
  const int i = blockIdx.x * 4 + wave;
  const int b = blockIdx.y;
  __shared__ __align__(16) float cb[D_MODEL];
  for (int d = tid; d < D_MODEL; d += 256) cb[d] = cbuf_g[b * D_MODEL + d];
  __syncthreads();
  const float* wr = w1 + (size_t)i * D_MODEL;
  float acc = 0.0f;
#pragma unroll
  for (int c = 0; c < 3; ++c) {
    int d = (lane << 2) + (c << 8);
    float4 wv = *(const float4*)(wr + d);
    float4 cv = *(const float4*)(&cb[d]);
    acc += wv.x * cv.x + wv.y * cv.y + wv.z * cv.z + wv.w * cv.w;
  }
#pragma unroll
  for (int o = 32; o; o >>= 1) acc += __shfl_xor(acc, o, 64);
  if (lane == 0) c1_g[b * D_MODEL + i] = tanhf(acc + b1[i]);
}

// ---------------- classifier stage C: logits ----------------
__global__ __launch_bounds__(256) void cls_logits(
    const float* __restrict__ c1_g, const float* __restrict__ w2,
    const float* __restrict__ b2, float* __restrict__ out) {
  const int b = blockIdx.x;
  const int tid = threadIdx.x;
  __shared__ float scratch[4];
#pragma unroll
  for (int jc = 0; jc < 2; ++jc) {
    float acc = 0.0f;
    for (int i = tid; i < D_MODEL; i += 256) acc += c1_g[b * D_MODEL + i] * w2[jc * D_MODEL + i];
#pragma unroll
    for (int o = 32; o; o >>= 1) acc += __shfl_xor(acc, o, 64);
    if ((tid & 63) == 0) scratch[tid >> 6] = acc;
    __syncthreads();
    if (tid == 0) out[b * 2 + jc] = scratch[0] + scratch[1] + scratch[2] + scratch[3] + b2[jc];
    __syncthreads();
  }
}

extern "C" void kernel_launch(void* const* d_in, const int* in_sizes, int n_in,
                              void* d_out, int out_size, void* d_ws, size_t ws_size,
                              hipStream_t stream) {
  const int*   tokens  = (const int*)d_in[0];
  const int*   mask    = (const int*)d_in[1];
  const float* emb     = (const float*)d_in[2];
  const float* in_w    = (const float*)d_in[3];
  const float* in_b    = (const float*)d_in[4];
  const float* out_w   = (const float*)d_in[5];
  const float* out_b   = (const float*)d_in[6];
  const float* ln1_s   = (const float*)d_in[7];
  const float* ln1_b   = (const float*)d_in[8];
  const float* ln2_s   = (const float*)d_in[9];
  const float* ln2_b   = (const float*)d_in[10];
  const float* ff_w1   = (const float*)d_in[11];
  const float* ff_b1   = (const float*)d_in[12];
  const float* ff_w2   = (const float*)d_in[13];
  const float* ff_b2   = (const float*)d_in[14];
  const float* pool_w  = (const float*)d_in[15];
  const float* pool_b  = (const float*)d_in[16];
  const float* cls_ln_s = (const float*)d_in[17];
  const float* cls_ln_b = (const float*)d_in[18];
  const float* cls_w1  = (const float*)d_in[19];
  const float* cls_b1  = (const float*)d_in[20];
  const float* cls_w2  = (const float*)d_in[21];
  const float* cls_b2  = (const float*)d_in[22];

  float* outp = (float*)d_out;
  float* ws = (float*)d_ws;
  const size_t XN = (size_t)8 * 1024 * 768;          // 6,291,456
  const size_t BIGU = (size_t)8192 * 3072;           // 25,165,824 ushorts
  unsigned short* x = (unsigned short*)ws;                       // fp16 residual
  unsigned short* bigu = (unsigned short*)(ws + XN);             // fp16 qkv / gelu
  unsigned short* h_f16 = (unsigned short*)(ws + XN + BIGU / 2); // fp16 activations
  unsigned short* wall = h_f16 + XN;                             // fp16 weight arena
  unsigned short* wall_in  = wall;                               // 4*2304*768
  unsigned short* wall_out = wall + (size_t)7077888;             // 4*768*768
  unsigned short* wall_ff1 = wall + (size_t)9437184;             // 4*3072*768
  unsigned short* wall_ff2 = wall + (size_t)18874368;            // 4*768*3072
  float* clsbuf = (float*)(wall + (size_t)28311552);
  float* sc_ws = clsbuf;                                         // 8192 floats
  float* partial = clsbuf + 8192;                                // 49152 floats
  float* cbuf_ws = partial + 49152;                              // 6144 floats
  float* c1_ws = cbuf_ws + 6144;                                 // 6144 floats
  float* pe_ws = c1_ws + 6144;                                   // 786432 floats
  float* allw = outp + 16;

  hipMemsetAsync(d_out, 0, (size_t)out_size * sizeof(float), stream);

  // PE table + upfront weight conversion (all layers)
  pe_init<<<3072, 256, 0, stream>>>(pe_ws);
  cvt_w_h<<<6912, 256, 0, stream>>>(in_w,  wall_in,  1769472);
  cvt_w_h<<<2304, 256, 0, stream>>>(out_w, wall_out,  589824);
  cvt_w_h<<<9216, 256, 0, stream>>>(ff_w1, wall_ff1, 2359296);
  cvt_w_h<<<9216, 256, 0, stream>>>(ff_w2, wall_ff2, 2359296);

  const int total4 = (int)(XN >> 2);
  embed_kernel<<<(total4 + 255) / 256, 256, 0, stream>>>(tokens, emb, pe_ws, x, total4);

  for (int l = 0; l < 4; ++l) {
    ln_kernel<<<2048, 256, 0, stream>>>(x, ln1_s + l * 768, ln1_b + l * 768, h_f16);
    gemm128<0><<<1152, 256, 0, stream>>>(h_f16, wall_in + (size_t)l * 1769472,
                                         in_b + l * 2304, bigu, 2304, 768, 18);
    attn_kernel<<<dim3(8, S_LEN / QT), 512, 0, stream>>>(bigu, mask, h_f16,
                                                         allw + (size_t)l * 8 * 1024 * 1024);
    gemm128<2><<<384, 256, 0, stream>>>(h_f16, wall_out + (size_t)l * 589824,
                                        out_b + l * 768, x, 768, 768, 6);
    ln_kernel<<<2048, 256, 0, stream>>>(x, ln2_s + l * 768, ln2_b + l * 768, h_f16);
    gemm128<1><<<1536, 256, 0, stream>>>(h_f16, wall_ff1 + (size_t)l * 2359296,
                                         ff_b1 + l * 3072, bigu, 3072, 768, 24);
    gemm128<2><<<384, 256, 0, stream>>>(bigu, wall_ff2 + (size_t)l * 2359296,
                                        ff_b2 + l * 768, x, 768, 3072, 6);
  }

  pool_score<<<2048, 256, 0, stream>>>(x, mask, pool_w, pool_b, sc_ws);
  pool_softmax<<<8, 256, 0, stream>>>(sc_ws);
  pool_sum<<<dim3(24, 8), 256, 0, stream>>>(x, sc_ws, partial);
  cls_ln<<<8, 256, 0, stream>>>(partial, cls_ln_s, cls_ln_b, cbuf_ws);
  cls_mlp1<<<dim3(192, 8), 256, 0, stream>>>(cbuf_ws, cls_w1, cls_b1, c1_ws);
  cls_logits<<<8, 256, 0, stream>>>(c1_ws, cls_w2, cls_b2, outp);
}

// Round 25
// 1226.459 us; speedup vs baseline: 1.1178x; 1.0360x over previous
//
#include <hip/hip_runtime.h>
#include <math.h>

#define S_LEN 1024
#define D_MODEL 768
#define NHEAD 12
#define NEG_INF -3.4028234663852886e38f

#define QT 32           // queries per attention block
#define KB 288          // key band per block = QT + 2*128

typedef _Float16 f16x8 __attribute__((ext_vector_type(8)));
typedef __attribute__((ext_vector_type(4))) float f32x4;

typedef const __attribute__((address_space(1))) unsigned int ga_u32;
typedef __attribute__((address_space(3))) unsigned int ls_u32;
__device__ __forceinline__ void gload16(const void* g, void* l) {
  __builtin_amdgcn_global_load_lds((ga_u32*)g, (ls_u32*)l, 16, 0, 0);
}

__device__ __forceinline__ float gelu_exact(float v) {
  return 0.5f * v * (1.0f + erff(v * 0.7071067811865475f));
}
__device__ __forceinline__ unsigned short f2h(float f) {
  union { _Float16 h; unsigned short u; } x; x.h = (_Float16)f; return x.u;
}
__device__ __forceinline__ float h2f(unsigned short u) {
  union { unsigned short u; _Float16 h; } x; x.u = u; return (float)x.h;
}

// ---------------- PE table init: pe[s][d], 1024x768 ----------------
__global__ __launch_bounds__(256) void pe_init(float* __restrict__ pe) {
  int i = blockIdx.x * 256 + threadIdx.x;
  if (i >= S_LEN * D_MODEL) return;
  int d = i % D_MODEL;
  int s = i / D_MODEL;
  float div = expf((float)(d & ~1) * (-9.210340371976184f / 768.0f));
  float ang = (float)s * div;
  pe[i] = (d & 1) ? cosf(ang) : sinf(ang);
}

// ---------------- embedding + PE table add -> fp16 residual ----------------
__global__ __launch_bounds__(256) void embed_kernel(
    const int* __restrict__ tok, const float* __restrict__ emb,
    const float* __restrict__ pe, unsigned short* __restrict__ X, int total4) {
  int i = blockIdx.x * 256 + threadIdx.x;
  if (i >= total4) return;
  int d4 = i % 192;
  int bs = i / 192;
  int s = bs & (S_LEN - 1);
  int t = tok[bs];
  float4 e = ((const float4*)emb)[(size_t)t * 192 + d4];
  float4 p = ((const float4*)pe)[(size_t)s * 192 + d4];
  ushort4 o;
  o.x = f2h(e.x + p.x); o.y = f2h(e.y + p.y);
  o.z = f2h(e.z + p.z); o.w = f2h(e.w + p.w);
  ((ushort4*)X)[i] = o;
}

// ---------------- weight convert: fp32 -> fp16 ----------------
__global__ __launch_bounds__(256) void cvt_w_h(
    const float* __restrict__ W, unsigned short* __restrict__ H, int n4) {
  int i = blockIdx.x * 256 + threadIdx.x;
  if (i >= n4) return;
  float4 w = ((const float4*)W)[i];
  ushort4 h;
  h.x = f2h(w.x); h.y = f2h(w.y); h.z = f2h(w.z); h.w = f2h(w.w);
  ((ushort4*)H)[i] = h;
}

// ---------------- LayerNorm (fp16 in): one wave per row, no LDS/barriers -------
__global__ __launch_bounds__(256) void ln_kernel(
    const unsigned short* __restrict__ X, const float* __restrict__ gam,
    const float* __restrict__ bet, unsigned short* __restrict__ Y) {
  const int tid = threadIdx.x;
  const int wave = tid >> 6, lane = tid & 63;
  const int row = blockIdx.x * 4 + wave;
  const unsigned short* xr = X + (size_t)row * D_MODEL;
  float v[12];
  float s = 0.0f;
#pragma unroll
  for (int c = 0; c < 3; ++c) {
    ushort4 u = *(const ushort4*)(xr + (lane << 2) + (c << 8));
    v[c * 4 + 0] = h2f(u.x); v[c * 4 + 1] = h2f(u.y);
    v[c * 4 + 2] = h2f(u.z); v[c * 4 + 3] = h2f(u.w);
    s += v[c * 4] + v[c * 4 + 1] + v[c * 4 + 2] + v[c * 4 + 3];
  }
#pragma unroll
  for (int o = 32; o; o >>= 1) s += __shfl_xor(s, o, 64);
  const float mean = s * (1.0f / 768.0f);
  float ss = 0.0f;
#pragma unroll
  for (int k = 0; k < 12; ++k) { float dd = v[k] - mean; ss += dd * dd; }
#pragma unroll
  for (int o = 32; o; o >>= 1) ss += __shfl_xor(ss, o, 64);
  const float rstd = rsqrtf(ss * (1.0f / 768.0f) + 1e-5f);
  unsigned short* yr = Y + (size_t)row * D_MODEL;
#pragma unroll
  for (int c = 0; c < 3; ++c) {
    const int d = (lane << 2) + (c << 8);
    float4 g = *(const float4*)(gam + d);
    float4 bb = *(const float4*)(bet + d);
    ushort4 o4;
    o4.x = f2h((v[c * 4 + 0] - mean) * rstd * g.x + bb.x);
    o4.y = f2h((v[c * 4 + 1] - mean) * rstd * g.y + bb.y);
    o4.z = f2h((v[c * 4 + 2] - mean) * rstd * g.z + bb.z);
    o4.w = f2h((v[c * 4 + 3] - mean) * rstd * g.w + bb.w);
    *(ushort4*)(yr + d) = o4;
  }
}

// ---------------- gemm128: 128x128 tile, BK=32, 4 waves, single-barrier 3-buffer --
// XCD chunk + 8x2 super-tile remap keeps per-XCD L2 working set ~2 MB.
// EPI 0: C_f16 = acc+bias   1: gelu   2: C_f16 += acc+bias (vectorized f16x8 RMW)
template <int EPI>
__global__ __launch_bounds__(256) void gemm128(
    const unsigned short* __restrict__ A, const unsigned short* __restrict__ W,
    const float* __restrict__ bias, void* __restrict__ Cv,
    int N, int K, int NX) {
  __shared__ __align__(16) unsigned short SH[24576];  // 3 buffers x (A 8KB + B 8KB)
  const int tid = threadIdx.x;
  const int nwg = gridDim.x;
  const int wg = ((blockIdx.x & 7) * (nwg >> 3)) + (blockIdx.x >> 3);
  const int SX = NX >> 1;
  const int st = wg >> 4, w16 = wg & 15;
  const int ty = (st / SX) * 8 + (w16 >> 1);
  const int tx = (st % SX) * 2 + (w16 & 1);
  const int m0 = ty << 7, n0 = tx << 7;
  const int wave = tid >> 6, lane = tid & 63;
  const int wr = (wave >> 1) << 6, wc = (wave & 1) << 6;
  const int lq = lane >> 4, lr = lane & 15;
  const int rA0 = (wave << 5) + (lane >> 2);
  const int rA1 = rA0 + 16;
  const int sl = lane & 3;
  const size_t gA0 = (size_t)(m0 + rA0) * K + ((sl ^ ((rA0 >> 1) & 3)) << 3);
  const size_t gA1 = (size_t)(m0 + rA1) * K + ((sl ^ ((rA1 >> 1) & 3)) << 3);
  const size_t gB0 = (size_t)(n0 + rA0) * K + ((sl ^ ((rA0 >> 1) & 3)) << 3);
  const size_t gB1 = (size_t)(n0 + rA1) * K + ((sl ^ ((rA1 >> 1) & 3)) << 3);
  const int lws = wave << 10;

  const int nt = K >> 5;
  auto stage = [&](int buf, int t) {
    unsigned short* base = SH + (buf << 13);
    const int kk = t << 5;
    gload16(A + gA0 + kk, base + lws);
    gload16(A + gA1 + kk, base + lws + 512);
    gload16(W + gB0 + kk, base + 4096 + lws);
    gload16(W + gB1 + kk, base + 4096 + lws + 512);
  };
  stage(0, 0);
  stage(1, 1);

  f32x4 acc[4][4] = {};
  int cb = 0;                         // compute-buffer index (cycles 0,1,2)
  for (int t = 0; t < nt; ++t) {
    if (t + 1 < nt) {
      asm volatile("s_waitcnt vmcnt(4)" ::: "memory");   // tile t's 4 loads done
    } else {
      asm volatile("s_waitcnt vmcnt(0)" ::: "memory");
    }
    __builtin_amdgcn_s_barrier();                         // everyone's tile t ready
    __builtin_amdgcn_sched_barrier(0);
    const unsigned short* As = SH + (cb << 13);
    const unsigned short* Bs = As + 4096;
    f16x8 af[4], bq[4];
#pragma unroll
    for (int i = 0; i < 4; ++i) {
      int r = wr + (i << 4) + lr;
      af[i] = *(const f16x8*)&As[r * 32 + ((lq ^ ((r >> 1) & 3)) << 3)];
    }
#pragma unroll
    for (int j = 0; j < 4; ++j) {
      int r = wc + (j << 4) + lr;
      bq[j] = *(const f16x8*)&Bs[r * 32 + ((lq ^ ((r >> 1) & 3)) << 3)];
    }
    if (t + 2 < nt) {                 // stage overlaps the MFMA cluster
      int sb = cb + 2; if (sb >= 3) sb -= 3;
      stage(sb, t + 2);
    }
    __builtin_amdgcn_sched_barrier(0);                    // pin stage before MFMAs
    __builtin_amdgcn_s_setprio(1);
#pragma unroll
    for (int i = 0; i < 4; ++i)
#pragma unroll
      for (int j = 0; j < 4; ++j)
        acc[i][j] = __builtin_amdgcn_mfma_f32_16x16x32_f16(af[i], bq[j], acc[i][j], 0, 0, 0);
    __builtin_amdgcn_s_setprio(0);
    cb = (cb == 2) ? 0 : cb + 1;
  }
  // bias per j-fragment column
  float bval[4];
#pragma unroll
  for (int j = 0; j < 4; ++j) bval[j] = bias[n0 + wc + (j << 4) + lr];

  unsigned short* C = (unsigned short*)Cv;
  __syncthreads();
  // repacked epilogue: two 64-row halves through LDS buffer 0, 16B/lane stores.
  // EPI 2 does a vectorized f16x8 RMW against the existing residual.
#pragma unroll
  for (int hh = 0; hh < 2; ++hh) {
    if ((wave >> 1) == hh) {
#pragma unroll
      for (int i = 0; i < 4; ++i)
#pragma unroll
        for (int j = 0; j < 4; ++j) {
          const int colb = wc + (j << 4) + lr;
#pragma unroll
          for (int r = 0; r < 4; ++r) {
            const int rowl = (i << 4) + (lq << 2) + r;
            float v = acc[i][j][r] + bval[j];
            if (EPI == 1) v = gelu_exact(v);
            const int ch = (colb >> 3) ^ (rowl & 7);
            SH[rowl * 128 + (ch << 3) + (colb & 7)] = f2h(v);
          }
        }
    }
    __syncthreads();
#pragma unroll
    for (int it = 0; it < 4; ++it) {
      const int cid = tid + (it << 8);
      const int row = cid >> 4, ch = cid & 15;
      const size_t coff = (size_t)(m0 + (hh << 6) + row) * N + n0 + (ch << 3);
      f16x8 a = *(const f16x8*)&SH[row * 128 + ((ch ^ (row & 7)) << 3)];
      if (EPI == 2) {
        f16x8 c8 = *(const f16x8*)&C[coff];
        a = a + c8;                      // v_pk_add_f16; fp16 inputs exact in fp32
      }
      *(f16x8*)&C[coff] = a;
    }
    __syncthreads();
  }
}

// ---------------- banded attention: MFMA QK^T + softmax + MFMA PV (fp16) ---------
// grid (b, qtile): XCD = b. K/Q staged via global_load_lds (linear LDS rows of
// 64 fp16, per-lane pre-swizzled global source). OOB K rows stay stale but are
// always masked to NEG_INF via kvalid. V reg-staged transposed (zero-filled
// OOB), slot swizzle (d>>3)&7.
__global__ __launch_bounds__(512) void attn_kernel(
    const unsigned short* __restrict__ qkv, const int* __restrict__ mask,
    unsigned short* __restrict__ attn_out, float* __restrict__ allw) {
  __shared__ __align__(16) unsigned short Ks[KB * 64];
  __shared__ __align__(16) unsigned short Vt[64 * 328];
  __shared__ __align__(16) unsigned short Qs[32 * 64];
  __shared__ __align__(16) unsigned short Ps[32 * 328];
  __shared__ __align__(16) float redmax[2][16][4];
  __shared__ __align__(16) float redsum[2][16][4];
  __shared__ int kvalid[KB];

  const int qt0 = blockIdx.y * QT;
  const int b = blockIdx.x;
  const int tid = threadIdx.x;
  const int w = tid >> 6, lane = tid & 63;
  const int lr = lane & 15, lg = lane >> 4;
  const int k0 = qt0 - 128;
  const int qh = w & 1, wq = w >> 1;
  const int nkt = (wq < 2) ? 5 : 4;

  for (int j = tid; j < KB; j += 512) {
    int key = k0 + j;
    kvalid[j] = (key >= 0 && key < S_LEN && mask[b * S_LEN + key] != 0) ? 1 : 0;
  }

  f32x4 pm[5] = {};
  const size_t rowbase = (size_t)(b * S_LEN) * 2304;
  const int qloc = lg << 2;
  const int qbase = (qh << 4) + qloc;
  const int sci = (w << 6) + lane;         // pass-0 chunk index for this thread
  const int sr = sci >> 3, sc8 = sci & 7;  // row / chunk-in-row

  for (int h = 0; h < NHEAD; ++h) {
    const int hoff = h << 6;
    // ---- Q via global_load_lds: 256 chunks, waves 0..3 (wave-uniform dest) ----
    if (w < 4) {
      unsigned short* qdst = Qs + ((size_t)(w << 6) << 3);
      gload16(qkv + rowbase + (size_t)(qt0 + sr) * 2304 + hoff + ((sc8 ^ (sr & 7)) << 3), qdst);
    }
    // ---- K via global_load_lds: 2304 chunks = 4.5 wave-passes ----
#pragma unroll
    for (int p = 0; p < 5; ++p) {
      const int cbase = (p << 9) + (w << 6);
      if (cbase < 2304) {
        const int ci = cbase + lane;
        const int r = ci >> 3, c = ci & 7;
        const int key = k0 + r;
        unsigned short* kdst = Ks + ((size_t)cbase << 3);
        if ((unsigned)key < (unsigned)S_LEN)
          gload16(qkv + rowbase + (size_t)key * 2304 + hoff + 768 + ((c ^ (r & 7)) << 3), kdst);
      }
    }
    // ---- V reg-staged transposed (zero-filled OOB) ----
    for (int idx = tid; idx < 2304; idx += 512) {
      int r = idx >> 3, c = idx & 7;
      int key = k0 + r;
      uint4 vv = {0, 0, 0, 0};
      if ((unsigned)key < (unsigned)S_LEN)
        vv = *(const uint4*)(qkv + rowbase + (size_t)key * 2304 + hoff + 1536 + (c << 3));
      const unsigned short* ve = (const unsigned short*)&vv;
      int jc = r >> 3, jw = r & 7;
#pragma unroll
      for (int e = 0; e < 8; ++e) {
        int d = (c << 3) + e;
        Vt[d * 328 + ((jc ^ ((d >> 3) & 7)) << 3) + jw] = ve[e];
      }
    }
    __syncthreads();

    f16x8 aq[2];
#pragma unroll
    for (int kc = 0; kc < 2; ++kc) {
      int r = (qh << 4) + lr;
      aq[kc] = *(f16x8*)&Qs[(r << 6) + ((((kc << 2) + lg) ^ (r & 7)) << 3)];
    }
    f32x4 sc[5];
    __builtin_amdgcn_s_setprio(1);
#pragma unroll
    for (int t = 0; t < 5; ++t) {
      sc[t] = (f32x4){0.0f, 0.0f, 0.0f, 0.0f};
      if (t < nkt) {
        int r = ((wq + (t << 2)) << 4) + lr;
#pragma unroll
        for (int kc = 0; kc < 2; ++kc) {
          f16x8 bk = *(f16x8*)&Ks[(r << 6) + ((((kc << 2) + lg) ^ (r & 7)) << 3)];
          sc[t] = __builtin_amdgcn_mfma_f32_16x16x32_f16(aq[kc], bk, sc[t], 0, 0, 0);
        }
      }
    }
    __builtin_amdgcn_s_setprio(0);
#pragma unroll
    for (int t = 0; t < 5; ++t) if (t < nkt) {
      int j = ((wq + (t << 2)) << 4) + lr;
      int okk = kvalid[j];
#pragma unroll
      for (int rg = 0; rg < 4; ++rg) {
        int q = qbase + rg;
        float s = sc[t][rg] * 0.125f;
        sc[t][rg] = (okk && j >= q && j <= q + 256) ? s : NEG_INF;
      }
    }
    float mx[4], zs[4];
#pragma unroll
    for (int rg = 0; rg < 4; ++rg) {
      float m = NEG_INF;
#pragma unroll
      for (int t = 0; t < 5; ++t) if (t < nkt) m = fmaxf(m, sc[t][rg]);
      mx[rg] = m;
    }
#pragma unroll
    for (int o = 1; o < 16; o <<= 1)
#pragma unroll
      for (int rg = 0; rg < 4; ++rg) mx[rg] = fmaxf(mx[rg], __shfl_xor(mx[rg], o, 64));
    if (lr == 0)
#pragma unroll
      for (int rg = 0; rg < 4; ++rg) redmax[qh][qloc + rg][wq] = mx[rg];
    __syncthreads();
#pragma unroll
    for (int rg = 0; rg < 4; ++rg) {
      f32x4 v = *(f32x4*)&redmax[qh][qloc + rg][0];
      mx[rg] = fmaxf(fmaxf(v[0], v[1]), fmaxf(v[2], v[3]));
      zs[rg] = 0.0f;
    }
#pragma unroll
    for (int t = 0; t < 5; ++t) if (t < nkt)
#pragma unroll
      for (int rg = 0; rg < 4; ++rg) {
        float e = expf(sc[t][rg] - mx[rg]);
        sc[t][rg] = e;
        zs[rg] += e;
      }
#pragma unroll
    for (int o = 1; o < 16; o <<= 1)
#pragma unroll
      for (int rg = 0; rg < 4; ++rg) zs[rg] += __shfl_xor(zs[rg], o, 64);
    if (lr == 0)
#pragma unroll
      for (int rg = 0; rg < 4; ++rg) redsum[qh][qloc + rg][wq] = zs[rg];
    __syncthreads();
#pragma unroll
    for (int rg = 0; rg < 4; ++rg) {
      f32x4 v = *(f32x4*)&redsum[qh][qloc + rg][0];
      zs[rg] = 1.0f / (v[0] + v[1] + v[2] + v[3]);
    }
#pragma unroll
    for (int t = 0; t < 5; ++t) if (t < nkt) {
      int j = ((wq + (t << 2)) << 4) + lr;
      int pc = j >> 3, pw = j & 7;
#pragma unroll
      for (int rg = 0; rg < 4; ++rg) {
        float p = sc[t][rg] * zs[rg];
        pm[t][rg] += p;
        int row = qbase + rg;
        Ps[row * 328 + ((pc ^ (row & 7)) << 3) + pw] = f2h(p);
      }
    }
    __syncthreads();
    {
      const int qt = w >> 2, dt = w & 3;
      const int ra = (qt << 4) + lr;
      const int rd = (dt << 4) + lr;
      f32x4 o4 = {0.0f, 0.0f, 0.0f, 0.0f};
      __builtin_amdgcn_s_setprio(1);
#pragma unroll
      for (int ks = 0; ks < 9; ++ks) {
        f16x8 pa = *(f16x8*)&Ps[ra * 328 + ((((ks << 2) + lg) ^ (ra & 7)) << 3)];
        f16x8 vb = *(f16x8*)&Vt[rd * 328 + ((((ks << 2) + lg) ^ ((rd >> 3) & 7)) << 3)];
        o4 = __builtin_amdgcn_mfma_f32_16x16x32_f16(pa, vb, o4, 0, 0, 0);
      }
      __builtin_amdgcn_s_setprio(0);
      unsigned short* op = attn_out +
          ((size_t)(b * S_LEN + qt0 + (qt << 4) + (lg << 2))) * D_MODEL + hoff + (dt << 4) + lr;
#pragma unroll
      for (int rg = 0; rg < 4; ++rg) op[(size_t)rg * D_MODEL] = f2h(o4[rg]);
    }
    __syncthreads();
  }

#pragma unroll
  for (int t = 0; t < 5; ++t) if (t < nkt) {
    int j = ((wq + (t << 2)) << 4) + lr;
    int key = k0 + j;
    if ((unsigned)key < (unsigned)S_LEN) {
      float* ap = allw + ((size_t)(b * S_LEN) + qt0 + qbase) * S_LEN + key;
#pragma unroll
      for (int rg = 0; rg < 4; ++rg) ap[(size_t)rg * S_LEN] = pm[t][rg] * (1.0f / 12.0f);
    }
  }
}

// ---------------- pooling stage 1: scores sc[b,s] = x·pool_w + pool_b ----------
__global__ __launch_bounds__(256) void pool_score(
    const unsigned short* __restrict__ X, const int* __restrict__ mask,
    const float* __restrict__ pool_w, const float* __restrict__ pool_b,
    float* __restrict__ sc) {
  const int tid = threadIdx.x;
  const int wave = tid >> 6, lane = tid & 63;
  const int row = blockIdx.x * 4 + wave;
  const unsigned short* xr = X + (size_t)row * D_MODEL;
  float acc = 0.0f;
#pragma unroll
  for (int c = 0; c < 3; ++c) {
    int d = (lane << 2) + (c << 8);
    ushort4 xv = *(const ushort4*)(xr + d);
    float4 wv = *(const float4*)(pool_w + d);
    acc += h2f(xv.x) * wv.x + h2f(xv.y) * wv.y + h2f(xv.z) * wv.z + h2f(xv.w) * wv.w;
  }
#pragma unroll
  for (int o = 32; o; o >>= 1) acc += __shfl_xor(acc, o, 64);
  if (lane == 0)
    sc[row] = (mask[row] == 0) ? NEG_INF : (acc + pool_b[0]);
}

// ---------------- pooling stage 2: softmax over S per batch (in-place) ---------
__global__ __launch_bounds__(256) void pool_softmax(float* __restrict__ sc) {
  __shared__ float scratch[4];
  __shared__ float buf[S_LEN];
  const int b = blockIdx.x;
  const int tid = threadIdx.x;
  float* sb = sc + b * S_LEN;
  float m = NEG_INF;
  for (int s = tid; s < S_LEN; s += 256) { buf[s] = sb[s]; m = fmaxf(m, buf[s]); }
#pragma unroll
  for (int o = 32; o; o >>= 1) m = fmaxf(m, __shfl_xor(m, o, 64));
  if ((tid & 63) == 0) scratch[tid >> 6] = m;
  __syncthreads();
  m = fmaxf(fmaxf(scratch[0], scratch[1]), fmaxf(scratch[2], scratch[3]));
  __syncthreads();
  float z = 0.0f;
  for (int s = tid; s < S_LEN; s += 256) { float e = expf(buf[s] - m); buf[s] = e; z += e; }
#pragma unroll
  for (int o = 32; o; o >>= 1) z += __shfl_xor(z, o, 64);
  if ((tid & 63) == 0) scratch[tid >> 6] = z;
  __syncthreads();
  float Z = scratch[0] + scratch[1] + scratch[2] + scratch[3];
  const float inv = 1.0f / Z;
  for (int s = tid; s < S_LEN; s += 256) sb[s] = buf[s] * inv;
}

// ---------------- pooling stage 3: partial weighted sums over s-chunks ---------
__global__ __launch_bounds__(256) void pool_sum(
    const unsigned short* __restrict__ X, const float* __restrict__ wgt,
    float* __restrict__ partial) {
  const int bx = blockIdx.x;            // dchunk*8 + schunk
  const int b = blockIdx.y;
  const int dchunk = bx >> 3, schunk = bx & 7;
  const int d = (dchunk << 8) + threadIdx.x;
  const int s0 = schunk << 7;
  const unsigned short* xb = X + ((size_t)(b << 10) + s0) * D_MODEL + d;
  const float* wb = wgt + (b << 10) + s0;
  float acc = 0.0f;
  for (int s = 0; s < 128; ++s) acc += wb[s] * h2f(xb[(size_t)s * D_MODEL]);
  partial[((size_t)((b << 3) + schunk)) * D_MODEL + d] = acc;
}

// ---------------- classifier stage A: reduce partials, tanh, LN -> cbuf --------
__global__ __launch_bounds__(256) void cls_ln(
    const float* __restrict__ partial,
    const float* __restrict__ ln_s, const float* __restrict__ ln_b,
    float* __restrict__ cbuf_g) {
  const int b = blockIdx.x;
  const int tid = threadIdx.x;
  __shared__ float scratch[4];
  __shared__ __align__(16) float pbuf[D_MODEL];
  for (int d = tid; d < D_MODEL; d += 256) {
    float acc = 0.0f;
#pragma unroll
    for (int p = 0; p < 8; ++p) acc += partial[((size_t)((b << 3) + p)) * D_MODEL + d];
    pbuf[d] = tanhf(acc);
  }
  __syncthreads();
  float ls = 0.0f;
  for (int d = tid; d < D_MODEL; d += 256) ls += pbuf[d];
#pragma unroll
  for (int o = 32; o; o >>= 1) ls += __shfl_xor(ls, o, 64);
  if ((tid & 63) == 0) scratch[tid >> 6] = ls;
  __syncthreads();
  float mean = (scratch[0] + scratch[1] + scratch[2] + scratch[3]) * (1.0f / 768.0f);
  __syncthreads();
  float vs = 0.0f;
  for (int d = tid; d < D_MODEL; d += 256) { float dd = pbuf[d] - mean; vs += dd * dd; }
#pragma unroll
  for (int o = 32; o; o >>= 1) vs += __shfl_xor(vs, o, 64);
  if ((tid & 63) == 0) scratch[tid >> 6] = vs;
  __syncthreads();
  float var = (scratch[0] + scratch[1] + scratch[2] + scratch[3]) * (1.0f / 768.0f);
  float rstd = rsqrtf(var + 1e-5f);
  for (int d = tid; d < D_MODEL; d += 256)
    cbuf_g[b * D_MODEL + d] = (pbuf[d] - mean) * rstd * ln_s[d] + ln_b[d];
}

// ---------------- classifier stage B: c1[b,i] = tanh(cbuf·w1[i] + b1[i]) --------
__global__ __launch_bounds__(256) void cls_mlp1(
    const float* __restrict__ cbuf_g, const float* __restrict__ w1,
    const float* __restrict__ b1, float* __restrict__ c1_g) {
  const int tid = threadIdx.x;
  const int wave = tid >> 6, lane = tid & 63;
  const int i = blockIdx.x * 4 + wave;
  const int b = blockIdx.y;
  __shared__ __align__(16) float cb[D_MODEL];
  for (int d = tid; d < D_MODEL; d += 256) cb[d] = cbuf_g[b * D_MODEL + d];
  __syncthreads();
  const float* wr = w1 + (size_t)i * D_MODEL;
  float acc = 0.0f;
#pragma unroll
  for (int c = 0; c < 3; ++c) {
    int d = (lane << 2) + (c << 8);
    float4 wv = *(const float4*)(wr + d);
    float4 cv = *(const float4*)(&cb[d]);
    acc += wv.x * cv.x + wv.y * cv.y + wv.z * cv.z + wv.w * cv.w;
  }
#pragma unroll
  for (int o = 32; o; o >>= 1) acc += __shfl_xor(acc, o, 64);
  if (lane == 0) c1_g[b * D_MODEL + i] = tanhf(acc + b1[i]);
}

// ---------------- classifier stage C: logits ----------------
__global__ __launch_bounds__(256) void cls_logits(
    const float* __restrict__ c1_g, const float* __restrict__ w2,
    const float* __restrict__ b2, float* __restrict__ out) {
  const int b = blockIdx.x;
  const int tid = threadIdx.x;
  __shared__ float scratch[4];
#pragma unroll
  for (int jc = 0; jc < 2; ++jc) {
    float acc = 0.0f;
    for (int i = tid; i < D_MODEL; i += 256) acc += c1_g[b * D_MODEL + i] * w2[jc * D_MODEL + i];
#pragma unroll
    for (int o = 32; o; o >>= 1) acc += __shfl_xor(acc, o, 64);
    if ((tid & 63) == 0) scratch[tid >> 6] = acc;
    __syncthreads();
    if (tid == 0) out[b * 2 + jc] = scratch[0] + scratch[1] + scratch[2] + scratch[3] + b2[jc];
    __syncthreads();
  }
}

extern "C" void kernel_launch(void* const* d_in, const int* in_sizes, int n_in,
                              void* d_out, int out_size, void* d_ws, size_t ws_size,
                              hipStream_t stream) {
  const int*   tokens  = (const int*)d_in[0];
  const int*   mask    = (const int*)d_in[1];
  const float* emb     = (const float*)d_in[2];
  const float* in_w    = (const float*)d_in[3];
  const float* in_b    = (const float*)d_in[4];
  const float* out_w   = (const float*)d_in[5];
  const float* out_b   = (const float*)d_in[6];
  const float* ln1_s   = (const float*)d_in[7];
  const float* ln1_b   = (const float*)d_in[8];
  const float* ln2_s   = (const float*)d_in[9];
  const float* ln2_b   = (const float*)d_in[10];
  const float* ff_w1   = (const float*)d_in[11];
  const float* ff_b1   = (const float*)d_in[12];
  const float* ff_w2   = (const float*)d_in[13];
  const float* ff_b2   = (const float*)d_in[14];
  const float* pool_w  = (const float*)d_in[15];
  const float* pool_b  = (const float*)d_in[16];
  const float* cls_ln_s = (const float*)d_in[17];
  const float* cls_ln_b = (const float*)d_in[18];
  const float* cls_w1  = (const float*)d_in[19];
  const float* cls_b1  = (const float*)d_in[20];
  const float* cls_w2  = (const float*)d_in[21];
  const float* cls_b2  = (const float*)d_in[22];

  float* outp = (float*)d_out;
  float* ws = (float*)d_ws;
  const size_t XN = (size_t)8 * 1024 * 768;          // 6,291,456
  const size_t BIGU = (size_t)8192 * 3072;           // 25,165,824 ushorts
  unsigned short* x = (unsigned short*)ws;                       // fp16 residual
  unsigned short* bigu = (unsigned short*)(ws + XN);             // fp16 qkv / gelu
  unsigned short* h_f16 = (unsigned short*)(ws + XN + BIGU / 2); // fp16 activations
  unsigned short* wall = h_f16 + XN;                             // fp16 weight arena
  unsigned short* wall_in  = wall;                               // 4*2304*768
  unsigned short* wall_out = wall + (size_t)7077888;             // 4*768*768
  unsigned short* wall_ff1 = wall + (size_t)9437184;             // 4*3072*768
  unsigned short* wall_ff2 = wall + (size_t)18874368;            // 4*768*3072
  float* clsbuf = (float*)(wall + (size_t)28311552);
  float* sc_ws = clsbuf;                                         // 8192 floats
  float* partial = clsbuf + 8192;                                // 49152 floats
  float* cbuf_ws = partial + 49152;                              // 6144 floats
  float* c1_ws = cbuf_ws + 6144;                                 // 6144 floats
  float* pe_ws = c1_ws + 6144;                                   // 786432 floats
  float* allw = outp + 16;

  hipMemsetAsync(d_out, 0, (size_t)out_size * sizeof(float), stream);

  // PE table + upfront weight conversion (all layers)
  pe_init<<<3072, 256, 0, stream>>>(pe_ws);
  cvt_w_h<<<6912, 256, 0, stream>>>(in_w,  wall_in,  1769472);
  cvt_w_h<<<2304, 256, 0, stream>>>(out_w, wall_out,  589824);
  cvt_w_h<<<9216, 256, 0, stream>>>(ff_w1, wall_ff1, 2359296);
  cvt_w_h<<<9216, 256, 0, stream>>>(ff_w2, wall_ff2, 2359296);

  const int total4 = (int)(XN >> 2);
  embed_kernel<<<(total4 + 255) / 256, 256, 0, stream>>>(tokens, emb, pe_ws, x, total4);

  for (int l = 0; l < 4; ++l) {
    ln_kernel<<<2048, 256, 0, stream>>>(x, ln1_s + l * 768, ln1_b + l * 768, h_f16);
    gemm128<0><<<1152, 256, 0, stream>>>(h_f16, wall_in + (size_t)l * 1769472,
                                         in_b + l * 2304, bigu, 2304, 768, 18);
    attn_kernel<<<dim3(8, S_LEN / QT), 512, 0, stream>>>(bigu, mask, h_f16,
                                                         allw + (size_t)l * 8 * 1024 * 1024);
    gemm128<2><<<384, 256, 0, stream>>>(h_f16, wall_out + (size_t)l * 589824,
                                        out_b + l * 768, x, 768, 768, 6);
    ln_kernel<<<2048, 256, 0, stream>>>(x, ln2_s + l * 768, ln2_b + l * 768, h_f16);
    gemm128<1><<<1536, 256, 0, stream>>>(h_f16, wall_ff1 + (size_t)l * 2359296,
                                         ff_b1 + l * 3072, bigu, 3072, 768, 24);
    gemm128<2><<<384, 256, 0, stream>>>(bigu, wall_ff2 + (size_t)l * 2359296,
                                        ff_b2 + l * 768, x, 768, 3072, 6);
  }

  pool_score<<<2048, 256, 0, stream>>>(x, mask, pool_w, pool_b, sc_ws);
  pool_softmax<<<8, 256, 0, stream>>>(sc_ws);
  pool_sum<<<dim3(24, 8), 256, 0, stream>>>(x, sc_ws, partial);
  cls_ln<<<8, 256, 0, stream>>>(partial, cls_ln_s, cls_ln_b, cbuf_ws);
  cls_mlp1<<<dim3(192, 8), 256, 0, stream>>>(cbuf_ws, cls_w1, cls_b1, c1_ws);
  cls_logits<<<8, 256, 0, stream>>>(c1_ws, cls_w2, cls_b2, outp);
}